// Round 14
// baseline (1151.856 us; speedup 1.0000x reference)
//
#include <hip/hip_runtime.h>
#include <hip/hip_bf16.h>
#include <float.h>
#include <limits.h>

#define NROWS 131072
#define DIM   256
#define NLVL  4
#define KC    1024
#define AMB   6.0f     // bf16-score ambiguity margin (validated r4-r13)
#define GUARD 0.25f    // parallel-vs-serial fp32 ordering guard (validated r10-r13)
#define REC   18       // amb record: row, cnt, cand[16]

typedef __attribute__((ext_vector_type(8))) short bf16x8;
typedef __attribute__((ext_vector_type(4))) float f32x4;
typedef __attribute__((ext_vector_type(4))) unsigned short us4;

__device__ __forceinline__ unsigned short f2b(float f){
  __hip_bfloat16 h = __float2bfloat16(f);
  return *reinterpret_cast<unsigned short*>(&h);
}

__device__ __forceinline__ float sqb(float x){
  float s = x * x;
  asm volatile("" : "+v"(s));
  return s;
}

__device__ __forceinline__ bool sless(float a, int ia, float b, int ib){
  return a < b || (a == b && ia < ib);
}

// async global->LDS 16B (DMA; LDS dest is wave-uniform base + lane*16)
__device__ __forceinline__ void gld16(const unsigned short* g, unsigned short* l){
  __builtin_amdgcn_global_load_lds(
      (const __attribute__((address_space(1))) unsigned int*)g,
      (__attribute__((address_space(3))) unsigned int*)l, 16, 0, 0);
}

// strict-< top-4 insert (tie-correct for ascending-index per-lane streams)
__device__ __forceinline__ void ins4(float (&s)[4], int (&ix)[4], float v, int ci){
  if (v < s[3]){
    s[3]=v; ix[3]=ci;
#pragma unroll
    for (int j = 3; j >= 1; --j){
      if (s[j] < s[j-1]){
        float t=s[j-1]; s[j-1]=s[j]; s[j]=t;
        int u=ix[j-1]; ix[j-1]=ix[j]; ix[j]=u;
      }
    }
  }
}

// ---------------- prep kernels (validated r4-r13) -----------------------
__global__ void zero8(int* __restrict__ p){
  if (threadIdx.x < 8) p[threadIdx.x] = 0;
}

__global__ void prep_cbb(const float* __restrict__ cb, unsigned short* __restrict__ cbb){
  const int wave = threadIdx.x >> 6, lane = threadIdx.x & 63;
  const int c = blockIdx.x * 4 + wave;
  const size_t off = (size_t)c * DIM + lane * 4;
  const float4 v = *reinterpret_cast<const float4*>(cb + off);
  us4 u = { f2b(v.x), f2b(v.y), f2b(v.z), f2b(v.w) };
  *reinterpret_cast<us4*>(cbb + off) = u;
}

__global__ void prep_cn(const float* __restrict__ cb, float* __restrict__ cnx){
  const int c = blockIdx.x * 64 + threadIdx.x;
  const float* p = cb + (size_t)c * DIM;
  float blk[2];
  for (int b = 0; b < 2; ++b){
    float r[8];
#pragma unroll
    for (int j = 0; j < 8; ++j) r[j] = sqb(p[b*128 + j]);
    for (int i = 8; i < 128; i += 8)
#pragma unroll
      for (int j = 0; j < 8; ++j) r[j] += sqb(p[b*128 + i + j]);
    blk[b] = ((r[0]+r[1]) + (r[2]+r[3])) + ((r[4]+r[5]) + (r[6]+r[7]));
  }
  cnx[c] = blk[0] + blk[1];
}

// ---------------- K1: LDS-tiled GEMM + lane-top4 classify ---------------
// r13 semantics; single-buffered As (49.5 KB LDS -> 3 blocks/CU), fully
// unrolled main loop, reads-before-barrier / DMA-under-MFMA schedule.
template<int LVL>
__global__ __launch_bounds__(512, 6)
void rvq_score(const float* __restrict__ feat,
               const float* __restrict__ cb32,
               const unsigned short* __restrict__ cbb_l,
               const float* __restrict__ cnx_l,
               int* __restrict__ idxw,
               int* __restrict__ cnt8,      // [0..3] amb, [4..7] hard
               int* __restrict__ arecs,     // [*][REC]
               int* __restrict__ hrows)
{
  __shared__ __align__(16) char smem[49664];
  unsigned short* Bs = (unsigned short*)smem;            // 32 KB
  unsigned short* As = (unsigned short*)(smem + 32768);  // 16 KB (single buf, linear)
  // aliases into As region (dead after main loop):
  float* rowm  = (float*)(smem + 32768);                 // [64*4]
  int*   cnt_l = (int*)(smem + 32768 + 1024);            // [64]
  int*   ovf_l = (int*)(smem + 32768 + 1280);            // [64]
  int*   cand_l= (int*)(smem + 32768 + 1536);            // [64*16]
  __shared__ int acnt_s, hcnt_s, abase_s, hbase_s;

  const int tid  = threadIdx.x;
  const int lane = tid & 63;
  const int wave = tid >> 6;
  const int r16  = lane & 15, quad = lane >> 4;
  const int wr   = wave >> 2, wc = wave & 3;
  const int rowbase = (int)blockIdx.x * 64;

  if (tid == 0){ acnt_s = 0; hcnt_s = 0; }

  // ---- per-thread staging constants (slot i -> (r,c); src chunk = c^x(r))
  const int i0 = tid,        r0 = i0 >> 2, c0i = i0 & 3;
  const int i1 = 512 + tid,  r1 = i1 >> 2, c1i = i1 & 3;
  const int x0 = (r0 & 3) ^ ((r0 >> 2) & 3);
  const int x1 = (r1 & 3) ^ ((r1 >> 2) & 3);
  const size_t gbase0 = (size_t)r0 * DIM + ((c0i ^ x0) << 3);
  const size_t gbase1 = (size_t)r1 * DIM + ((c1i ^ x1) << 3);
  unsigned short* ldst0 = As + i0 * 8;    // byte off i0*16
  unsigned short* ldst1 = As + i1 * 8;

#define STAGE(TI) { \
    const size_t toff = (size_t)((TI) >> 3) * (256*DIM) + ((TI) & 7) * 32; \
    gld16(cbb_l + gbase0 + toff, ldst0); \
    gld16(cbb_l + gbase1 + toff, ldst1); \
  }

  // prologue: tile 0 in flight during B build
  STAGE(0)

  // ---- phase 0: residual rows -> LDS (exact fp32 chain -> bf16) --------
  {
    const int row = tid >> 3;
    const int d0 = (tid & 7) * 32;
    const int grow = rowbase + row;
    int hist[NLVL > 1 ? NLVL : 1];
#pragma unroll
    for (int j = 0; j < LVL; ++j) hist[j] = idxw[j * NROWS + grow];
#pragma unroll
    for (int c4 = 0; c4 < 4; ++c4){
      const int d = d0 + c4*8;
      const float* p = feat + (size_t)grow * DIM + d;
      float4 f0 = *reinterpret_cast<const float4*>(p);
      float4 f1 = *reinterpret_cast<const float4*>(p + 4);
#pragma unroll
      for (int j = 0; j < LVL; ++j){
        const float* cp = cb32 + ((size_t)j * KC + hist[j]) * DIM + d;
        const float4 c0 = *reinterpret_cast<const float4*>(cp);
        const float4 c1 = *reinterpret_cast<const float4*>(cp + 4);
        f0.x -= c0.x; f0.y -= c0.y; f0.z -= c0.z; f0.w -= c0.w;
        f1.x -= c1.x; f1.y -= c1.y; f1.z -= c1.z; f1.w -= c1.w;
      }
      bf16x8 b;
      b[0]=(short)f2b(f0.x); b[1]=(short)f2b(f0.y); b[2]=(short)f2b(f0.z); b[3]=(short)f2b(f0.w);
      b[4]=(short)f2b(f1.x); b[5]=(short)f2b(f1.y); b[6]=(short)f2b(f1.z); b[7]=(short)f2b(f1.w);
      *reinterpret_cast<bf16x8*>(&Bs[row*256 + (((d >> 3) ^ (row & 7)) << 3)]) = b;
    }
  }

  f32x4 acc[2][4];
#pragma unroll
  for (int mi = 0; mi < 2; ++mi)
#pragma unroll
    for (int ni = 0; ni < 4; ++ni) acc[mi][ni] = (f32x4){0.f,0.f,0.f,0.f};

  float ts[2][4] = {{FLT_MAX,FLT_MAX,FLT_MAX,FLT_MAX},{FLT_MAX,FLT_MAX,FLT_MAX,FLT_MAX}};
  int   ti[2][4] = {{INT_MAX,INT_MAX,INT_MAX,INT_MAX},{INT_MAX,INT_MAX,INT_MAX,INT_MAX}};

  // ---- Af/Bf per-lane LDS offsets, loop-invariant parts ----------------
  int offA[4];
#pragma unroll
  for (int ni = 0; ni < 4; ++ni){
    const int arow = wc*64 + ni*16 + r16;
    const int xa = (arow & 3) ^ ((arow >> 2) & 3);
    offA[ni] = arow*32 + ((quad ^ xa) << 3);
  }

  __syncthreads();   // tile 0 drained; Bs complete

#pragma unroll
  for (int i = 0; i < 32; ++i){
    const int ct = i >> 3, kt = i & 7;

    // ---- read fragments of tile i (As holds tile i) --------------------
    bf16x8 Bf[2], Af[4];
#pragma unroll
    for (int mi = 0; mi < 2; ++mi){
      const int row = wr*32 + mi*16 + r16;
      Bf[mi] = *reinterpret_cast<const bf16x8*>(
          &Bs[row*256 + (((kt*4 + quad) ^ (row & 7)) << 3)]);
    }
#pragma unroll
    for (int ni = 0; ni < 4; ++ni)
      Af[ni] = *reinterpret_cast<const bf16x8*>(&As[offA[ni]]);

    __syncthreads();                 // all reads done -> As overwrite safe
    if (i < 31) STAGE(i + 1)         // DMA in flight under MFMA below

#pragma unroll
    for (int ni = 0; ni < 4; ++ni){
      acc[0][ni] = __builtin_amdgcn_mfma_f32_16x16x32_bf16(Af[ni], Bf[0], acc[0][ni], 0, 0, 0);
      acc[1][ni] = __builtin_amdgcn_mfma_f32_16x16x32_bf16(Af[ni], Bf[1], acc[1][ni], 0, 0, 0);
    }

    if (kt == 7){
#pragma unroll
      for (int mi = 0; mi < 2; ++mi)
#pragma unroll
        for (int ni = 0; ni < 4; ++ni){
          const int c0 = ct*256 + wc*64 + ni*16 + quad*4;
          const float4 cn = *reinterpret_cast<const float4*>(cnx_l + c0);
          const f32x4 a = acc[mi][ni];
          ins4(ts[mi], ti[mi], cn.x - 2.f*a[0], c0+0);
          ins4(ts[mi], ti[mi], cn.y - 2.f*a[1], c0+1);
          ins4(ts[mi], ti[mi], cn.z - 2.f*a[2], c0+2);
          ins4(ts[mi], ti[mi], cn.w - 2.f*a[3], c0+3);
          acc[mi][ni] = (f32x4){0.f,0.f,0.f,0.f};
        }
    }
    __syncthreads();                 // DMA drained: As holds tile i+1
  }
#undef STAGE

  // ---- rowmin publish + list init (validated r12/r13) ------------------
#pragma unroll
  for (int mi = 0; mi < 2; ++mi){
    float m = ts[mi][0];
    m = fminf(m, __shfl_xor(m, 16));
    m = fminf(m, __shfl_xor(m, 32));
    if (quad == 0) rowm[(wr*32 + mi*16 + r16)*4 + wc] = m;
  }
  if (tid < 64){ cnt_l[tid] = 0; ovf_l[tid] = 0; }
  __syncthreads();

  // ---- per-lane margin emission (lane-overflow -> hard) -----------------
#pragma unroll
  for (int mi = 0; mi < 2; ++mi){
    const int row = wr*32 + mi*16 + r16;
    const float m1 = fminf(fminf(rowm[row*4], rowm[row*4+1]),
                           fminf(rowm[row*4+2], rowm[row*4+3]));
    const float thr = m1 + AMB;
#pragma unroll
    for (int e = 0; e < 4; ++e){
      if (ts[mi][e] <= thr){
        const int pos = atomicAdd(&cnt_l[row], 1);
        if (pos < 16) cand_l[row*16 + pos] = ti[mi][e];
      }
    }
    if (ts[mi][3] <= thr) ovf_l[row] = 1;   // lane may have dropped entries
  }
  __syncthreads();

  // ---- classify & emit --------------------------------------------------
  int apos = -1, hpos = -1, myc = 0;
  if (tid < 64){
    myc = cnt_l[tid];
    if (!ovf_l[tid] && myc == 1){
      idxw[LVL * NROWS + rowbase + tid] = cand_l[tid*16];
    } else if (!ovf_l[tid] && myc <= 16){
      apos = atomicAdd(&acnt_s, 1);
    } else {
      hpos = atomicAdd(&hcnt_s, 1);
    }
  }
  __syncthreads();
  if (tid == 0){
    abase_s = acnt_s ? atomicAdd(&cnt8[LVL], acnt_s) : 0;
    hbase_s = hcnt_s ? atomicAdd(&cnt8[4 + LVL], hcnt_s) : 0;
  }
  __syncthreads();
  if (apos >= 0){
    int* rp = arecs + (size_t)(abase_s + apos) * REC;
    rp[0] = rowbase + tid; rp[1] = myc;
    for (int e = 0; e < myc; ++e) rp[2+e] = cand_l[tid*16 + e];
  }
  if (hpos >= 0) hrows[hbase_s + hpos] = rowbase + tid;
}

// ---------------- K2a: amb rows (verbatim r12/r13, validated) -----------
template<int LVL>
__global__ __launch_bounds__(256)
void rvq_amb(const float* __restrict__ feat,
             const float* __restrict__ cb32,
             const float* __restrict__ cnx_l,
             int* __restrict__ idxw,
             const int* __restrict__ cnt8,
             const int* __restrict__ arecs)
{
  __shared__ float rres[16][260];
  const int tid = threadIdx.x;
  const int g = tid >> 4, q = tid & 15;
  const int cnt = cnt8[LVL];
  const float* cbl = cb32 + (size_t)LVL * KC * DIM;

  for (int rr = blockIdx.x * 16 + g; rr < cnt; rr += gridDim.x * 16){
    const int* rp = arecs + (size_t)rr * REC;
    const int grow = rp[0];
    const int c = rp[1];

    float4 rv[4];
#pragma unroll
    for (int i4 = 0; i4 < 4; ++i4){
      const int d = q*16 + i4*4;
      float4 w = *reinterpret_cast<const float4*>(feat + (size_t)grow * DIM + d);
#pragma unroll
      for (int j2 = 0; j2 < LVL; ++j2){
        const int kj = idxw[(size_t)j2 * NROWS + grow];
        const float4 cv = *reinterpret_cast<const float4*>(
            cb32 + ((size_t)j2 * KC + kj) * DIM + d);
        w.x -= cv.x; w.y -= cv.y; w.z -= cv.z; w.w -= cv.w;
      }
      rv[i4] = w;
      *reinterpret_cast<float4*>(&rres[g][d]) = w;
    }

    float m1 = FLT_MAX, m2 = FLT_MAX; int i1 = INT_MAX;
    for (int qq = 0; qq < c; ++qq){
      const int ci = rp[2+qq];
      const float* cp = cbl + (size_t)ci * DIM + q*16;
      float pa = 0.f;
#pragma unroll
      for (int j = 0; j < 4; ++j){
        const float4 cv = *reinterpret_cast<const float4*>(cp + j*4);
        pa = fmaf(rv[j].x, cv.x, pa); pa = fmaf(rv[j].y, cv.y, pa);
        pa = fmaf(rv[j].z, cv.z, pa); pa = fmaf(rv[j].w, cv.w, pa);
      }
#pragma unroll
      for (int m = 1; m < 16; m <<= 1) pa += __shfl_xor(pa, m);
      const float sc = cnx_l[ci] - 2.0f * pa;
      if (sless(sc, ci, m1, i1)){ m2 = m1; m1 = sc; i1 = ci; }
      else m2 = fminf(m2, sc);
    }

    int winner = i1;
    if (!(m2 - m1 > GUARD)){
      float bs = FLT_MAX; int bi = INT_MAX;
      for (int k = q; k < c; k += 16){
        const int ci = rp[2+k];
        float a = 0.f;
        for (int d4 = 0; d4 < 64; ++d4){
          const float4 cv = *reinterpret_cast<const float4*>(cbl + (size_t)ci * DIM + d4*4);
          const float4 rw = *reinterpret_cast<const float4*>(&rres[g][d4*4]);
          a = fmaf(rw.x, cv.x, a); a = fmaf(rw.y, cv.y, a);
          a = fmaf(rw.z, cv.z, a); a = fmaf(rw.w, cv.w, a);
        }
        const float sc = cnx_l[ci] - 2.0f * a;
        if (sless(sc, ci, bs, bi)){ bs = sc; bi = ci; }
      }
#pragma unroll
      for (int m = 1; m < 16; m <<= 1){
        const float ob = __shfl_xor(bs, m); const int oi = __shfl_xor(bi, m);
        if (sless(ob, oi, bs, bi)){ bs = ob; bi = oi; }
      }
      winner = bi;
    }
    if (q == 0) idxw[(size_t)LVL * NROWS + grow] = winner;
  }
}

// ---------------- K2b: hard rows (verbatim r11-r13, validated) ----------
template<int LVL>
__global__ __launch_bounds__(256)
void rvq_hard(const float* __restrict__ feat,
              const float* __restrict__ cb32,
              const float* __restrict__ cnx_l,
              int* __restrict__ idxw,
              const int* __restrict__ cnt8,
              const int* __restrict__ hrows)
{
  __shared__ float rres[260];
  __shared__ float scb[1024];
  __shared__ float wmn[4];
  __shared__ float wbs[4];
  __shared__ int   wbi[4];
  const int tid = threadIdx.x;
  const int g = tid >> 4, q = tid & 15;
  const int wv = tid >> 6, ln = tid & 63;
  const int cnt = cnt8[4 + LVL];
  const float* cbl = cb32 + (size_t)LVL * KC * DIM;

  for (int r = blockIdx.x; r < cnt; r += gridDim.x){
    const int grow = hrows[r];
    if (tid < 16){
#pragma unroll
      for (int i4 = 0; i4 < 4; ++i4){
        const int d = tid*16 + i4*4;
        float4 w = *reinterpret_cast<const float4*>(feat + (size_t)grow * DIM + d);
#pragma unroll
        for (int j2 = 0; j2 < LVL; ++j2){
          const int kj = idxw[(size_t)j2 * NROWS + grow];
          const float4 cv = *reinterpret_cast<const float4*>(
              cb32 + ((size_t)j2 * KC + kj) * DIM + d);
          w.x -= cv.x; w.y -= cv.y; w.z -= cv.z; w.w -= cv.w;
        }
        *reinterpret_cast<float4*>(&rres[d]) = w;
      }
    }
    __syncthreads();

    float4 rv[4];
#pragma unroll
    for (int j = 0; j < 4; ++j)
      rv[j] = *reinterpret_cast<const float4*>(&rres[q*16 + j*4]);

    for (int t = 0; t < 64; ++t){
      const int ci = g*64 + t;
      float pa = 0.f;
#pragma unroll
      for (int j = 0; j < 4; ++j){
        const float4 cv = *reinterpret_cast<const float4*>(
            cbl + (size_t)ci * DIM + q*16 + j*4);
        pa = fmaf(rv[j].x, cv.x, pa); pa = fmaf(rv[j].y, cv.y, pa);
        pa = fmaf(rv[j].z, cv.z, pa); pa = fmaf(rv[j].w, cv.w, pa);
      }
#pragma unroll
      for (int m = 1; m < 16; m <<= 1) pa += __shfl_xor(pa, m);
      if (q == 0) scb[ci] = cnx_l[ci] - 2.0f * pa;
    }
    __syncthreads();

    float mn = fminf(fminf(scb[tid], scb[tid+256]), fminf(scb[tid+512], scb[tid+768]));
#pragma unroll
    for (int m = 1; m < 64; m <<= 1) mn = fminf(mn, __shfl_xor(mn, m));
    if (ln == 0) wmn[wv] = mn;
    __syncthreads();
    const float m1p = fminf(fminf(wmn[0], wmn[1]), fminf(wmn[2], wmn[3]));
    const float thr = m1p + GUARD;

    float bs = FLT_MAX; int bi = INT_MAX;
#pragma unroll
    for (int k = 0; k < 4; ++k){
      const int ci = tid + k*256;
      if (scb[ci] <= thr){
        float a = 0.f;
        for (int d4 = 0; d4 < 64; ++d4){
          const float4 cv = *reinterpret_cast<const float4*>(cbl + (size_t)ci * DIM + d4*4);
          const float4 rw = *reinterpret_cast<const float4*>(&rres[d4*4]);
          a = fmaf(rw.x, cv.x, a); a = fmaf(rw.y, cv.y, a);
          a = fmaf(rw.z, cv.z, a); a = fmaf(rw.w, cv.w, a);
        }
        const float sc = cnx_l[ci] - 2.0f * a;
        if (sless(sc, ci, bs, bi)){ bs = sc; bi = ci; }
      }
    }
#pragma unroll
    for (int m = 1; m < 64; m <<= 1){
      const float ob = __shfl_xor(bs, m); const int oi = __shfl_xor(bi, m);
      if (sless(ob, oi, bs, bi)){ bs = ob; bi = oi; }
    }
    if (ln == 0){ wbs[wv] = bs; wbi[wv] = bi; }
    __syncthreads();
    if (tid == 0){
      float fb = wbs[0]; int fi = wbi[0];
#pragma unroll
      for (int w = 1; w < 4; ++w)
        if (sless(wbs[w], wbi[w], fb, fi)){ fb = wbs[w]; fi = wbi[w]; }
      idxw[(size_t)LVL * NROWS + grow] = fi;
    }
    __syncthreads();
  }
}

// ---------------- K3: final output = q0+q1+q2+q3 (validated r5-r13) -----
__global__ __launch_bounds__(256)
void rvq_out(const float* __restrict__ cb32,
             const int* __restrict__ idxw,
             float* __restrict__ out)
{
  const int tid = threadIdx.x;
  const int row = tid >> 4, sub = tid & 15;
  const size_t n = (size_t)blockIdx.x * 16 + row;
  int hist[NLVL];
#pragma unroll
  for (int j2 = 0; j2 < 4; ++j2) hist[j2] = idxw[(size_t)j2 * NROWS + n];
#pragma unroll
  for (int i = 0; i < 4; ++i){
    const int d = sub*4 + i*64;
    float4 a = *reinterpret_cast<const float4*>(
        cb32 + ((size_t)0 * KC + hist[0]) * DIM + d);
#pragma unroll
    for (int j2 = 1; j2 < 4; ++j2){
      const float4 qv = *reinterpret_cast<const float4*>(
          cb32 + ((size_t)j2 * KC + hist[j2]) * DIM + d);
      a.x += qv.x; a.y += qv.y; a.z += qv.z; a.w += qv.w;
    }
    *reinterpret_cast<float4*>(out + n*DIM + d) = a;
  }
}

extern "C" void kernel_launch(void* const* d_in, const int* in_sizes, int n_in,
                              void* d_out, int out_size, void* d_ws, size_t ws_size,
                              hipStream_t stream){
  const float* feat = (const float*)d_in[0];
  const float* cb32 = (const float*)d_in[1];
  float* out = (float*)d_out;

  char* ws = (char*)d_ws;
  float* cnx  = (float*)(ws);                              // 16 KB
  int*   cnt8 = (int*)(ws + 16384);                        // 8 counters
  unsigned short* cbb = (unsigned short*)(ws + 32768);     // 2 MB
  int*   idxw = (int*)(ws + 32768 + 2097152);              // 2 MB
  int*   arecs = (int*)(ws + 32768 + 2097152 + 2097152);   // 9.5 MB
  int*   hrows = (int*)(ws + 32768 + 2097152 + 2097152 + 9961472); // 512 KB

  zero8<<<1, 64, 0, stream>>>(cnt8);
  prep_cbb<<<1024, 256, 0, stream>>>(cb32, cbb);
  prep_cn<<<64, 64, 0, stream>>>(cb32, cnx);

#define LVL_STEP(L) \
  rvq_score<L><<<2048, 512, 0, stream>>>(feat, cb32, cbb + (size_t)L*KC*DIM, \
      cnx + L*KC, idxw, cnt8, arecs, hrows); \
  rvq_amb<L><<<2048, 256, 0, stream>>>(feat, cb32, cnx + L*KC, idxw, cnt8, arecs); \
  rvq_hard<L><<<512, 256, 0, stream>>>(feat, cb32, cnx + L*KC, idxw, cnt8, hrows);

  LVL_STEP(0)
  LVL_STEP(1)
  LVL_STEP(2)
  LVL_STEP(3)
#undef LVL_STEP

  rvq_out<<<8192, 256, 0, stream>>>(cb32, idxw, out);
}

// Round 16
// 1133.696 us; speedup vs baseline: 1.0160x; 1.0160x over previous
//
#include <hip/hip_runtime.h>
#include <hip/hip_bf16.h>
#include <float.h>
#include <limits.h>

#define NROWS 131072
#define DIM   256
#define NLVL  4
#define KC    1024
#define AMB   6.0f     // bf16-score ambiguity margin (validated r4-r14)
#define GUARD 0.25f    // parallel-vs-serial fp32 ordering guard (validated r10-r14)
#define REC   18       // amb record: row, cnt, cand[16]

typedef __attribute__((ext_vector_type(8))) short bf16x8;
typedef __attribute__((ext_vector_type(4))) float f32x4;
typedef __attribute__((ext_vector_type(4))) unsigned short us4;

__device__ __forceinline__ unsigned short f2b(float f){
  __hip_bfloat16 h = __float2bfloat16(f);
  return *reinterpret_cast<unsigned short*>(&h);
}

__device__ __forceinline__ float sqb(float x){
  float s = x * x;
  asm volatile("" : "+v"(s));
  return s;
}

__device__ __forceinline__ bool sless(float a, int ia, float b, int ib){
  return a < b || (a == b && ia < ib);
}

// async global->LDS 16B (DMA; LDS dest is wave-uniform base + lane*16)
__device__ __forceinline__ void gld16(const unsigned short* g, unsigned short* l){
  __builtin_amdgcn_global_load_lds(
      (const __attribute__((address_space(1))) unsigned int*)g,
      (__attribute__((address_space(3))) unsigned int*)l, 16, 0, 0);
}

// strict-< top-4 insert (tie-correct for ascending-index per-lane streams)
__device__ __forceinline__ void ins4(float (&s)[4], int (&ix)[4], float v, int ci){
  if (v < s[3]){
    s[3]=v; ix[3]=ci;
#pragma unroll
    for (int j = 3; j >= 1; --j){
      if (s[j] < s[j-1]){
        float t=s[j-1]; s[j-1]=s[j]; s[j]=t;
        int u=ix[j-1]; ix[j-1]=ix[j]; ix[j]=u;
      }
    }
  }
}

// ---------------- prep kernels (validated r4-r14) -----------------------
__global__ void zero8(int* __restrict__ p){
  if (threadIdx.x < 8) p[threadIdx.x] = 0;
}

__global__ void prep_cbb(const float* __restrict__ cb, unsigned short* __restrict__ cbb){
  const int wave = threadIdx.x >> 6, lane = threadIdx.x & 63;
  const int c = blockIdx.x * 4 + wave;
  const size_t off = (size_t)c * DIM + lane * 4;
  const float4 v = *reinterpret_cast<const float4*>(cb + off);
  us4 u = { f2b(v.x), f2b(v.y), f2b(v.z), f2b(v.w) };
  *reinterpret_cast<us4*>(cbb + off) = u;
}

__global__ void prep_cn(const float* __restrict__ cb, float* __restrict__ cnx){
  const int c = blockIdx.x * 64 + threadIdx.x;
  const float* p = cb + (size_t)c * DIM;
  float blk[2];
  for (int b = 0; b < 2; ++b){
    float r[8];
#pragma unroll
    for (int j = 0; j < 8; ++j) r[j] = sqb(p[b*128 + j]);
    for (int i = 8; i < 128; i += 8)
#pragma unroll
      for (int j = 0; j < 8; ++j) r[j] += sqb(p[b*128 + i + j]);
    blk[b] = ((r[0]+r[1]) + (r[2]+r[3])) + ((r[4]+r[5]) + (r[6]+r[7]));
  }
  cnx[c] = blk[0] + blk[1];
}

// ---------------- K1: LDS-tiled GEMM + lane-top4 classify ---------------
// r14 semantics verbatim; single-buffered As (50 KB LDS -> 3 blocks/CU),
// plain (non-unrolled) main loop, launch_bounds(512,4) — no spill.
template<int LVL>
__global__ __launch_bounds__(512, 4)
void rvq_score(const float* __restrict__ feat,
               const float* __restrict__ cb32,
               const unsigned short* __restrict__ cbb_l,
               const float* __restrict__ cnx_l,
               int* __restrict__ idxw,
               int* __restrict__ cnt8,      // [0..3] amb, [4..7] hard
               int* __restrict__ arecs,     // [*][REC]
               int* __restrict__ hrows)
{
  __shared__ __align__(16) char smem[49664];
  unsigned short* Bs = (unsigned short*)smem;            // 32 KB
  unsigned short* As = (unsigned short*)(smem + 32768);  // 16 KB (single buf, linear)
  // aliases into As region (dead after main loop):
  float* rowm  = (float*)(smem + 32768);                 // [64*4]
  int*   cnt_l = (int*)(smem + 32768 + 1024);            // [64]
  int*   ovf_l = (int*)(smem + 32768 + 1280);            // [64]
  int*   cand_l= (int*)(smem + 32768 + 1536);            // [64*16]
  __shared__ int acnt_s, hcnt_s, abase_s, hbase_s;

  const int tid  = threadIdx.x;
  const int lane = tid & 63;
  const int wave = tid >> 6;
  const int r16  = lane & 15, quad = lane >> 4;
  const int wr   = wave >> 2, wc = wave & 3;
  const int rowbase = (int)blockIdx.x * 64;

  if (tid == 0){ acnt_s = 0; hcnt_s = 0; }

  // ---- per-thread staging constants (slot i -> (r,c); src chunk = c^x(r))
  const int i0 = tid,        r0 = i0 >> 2, c0i = i0 & 3;
  const int i1 = 512 + tid,  r1 = i1 >> 2, c1i = i1 & 3;
  const int x0 = (r0 & 3) ^ ((r0 >> 2) & 3);
  const int x1 = (r1 & 3) ^ ((r1 >> 2) & 3);
  const size_t gbase0 = (size_t)r0 * DIM + ((c0i ^ x0) << 3);
  const size_t gbase1 = (size_t)r1 * DIM + ((c1i ^ x1) << 3);
  unsigned short* ldst0 = As + i0 * 8;    // byte off i0*16
  unsigned short* ldst1 = As + i1 * 8;

#define STAGE(TI) { \
    const size_t toff = (size_t)((TI) >> 3) * (256*DIM) + ((TI) & 7) * 32; \
    gld16(cbb_l + gbase0 + toff, ldst0); \
    gld16(cbb_l + gbase1 + toff, ldst1); \
  }

  // prologue: tile 0 in flight during B build
  STAGE(0)

  // ---- phase 0: residual rows -> LDS (exact fp32 chain -> bf16) --------
  {
    const int row = tid >> 3;
    const int d0 = (tid & 7) * 32;
    const int grow = rowbase + row;
    int hist[NLVL > 1 ? NLVL : 1];
#pragma unroll
    for (int j = 0; j < LVL; ++j) hist[j] = idxw[j * NROWS + grow];
#pragma unroll
    for (int c4 = 0; c4 < 4; ++c4){
      const int d = d0 + c4*8;
      const float* p = feat + (size_t)grow * DIM + d;
      float4 f0 = *reinterpret_cast<const float4*>(p);
      float4 f1 = *reinterpret_cast<const float4*>(p + 4);
#pragma unroll
      for (int j = 0; j < LVL; ++j){
        const float* cp = cb32 + ((size_t)j * KC + hist[j]) * DIM + d;
        const float4 c0 = *reinterpret_cast<const float4*>(cp);
        const float4 c1 = *reinterpret_cast<const float4*>(cp + 4);
        f0.x -= c0.x; f0.y -= c0.y; f0.z -= c0.z; f0.w -= c0.w;
        f1.x -= c1.x; f1.y -= c1.y; f1.z -= c1.z; f1.w -= c1.w;
      }
      bf16x8 b;
      b[0]=(short)f2b(f0.x); b[1]=(short)f2b(f0.y); b[2]=(short)f2b(f0.z); b[3]=(short)f2b(f0.w);
      b[4]=(short)f2b(f1.x); b[5]=(short)f2b(f1.y); b[6]=(short)f2b(f1.z); b[7]=(short)f2b(f1.w);
      *reinterpret_cast<bf16x8*>(&Bs[row*256 + (((d >> 3) ^ (row & 7)) << 3)]) = b;
    }
  }

  f32x4 acc[2][4];
#pragma unroll
  for (int mi = 0; mi < 2; ++mi)
#pragma unroll
    for (int ni = 0; ni < 4; ++ni) acc[mi][ni] = (f32x4){0.f,0.f,0.f,0.f};

  float ts[2][4] = {{FLT_MAX,FLT_MAX,FLT_MAX,FLT_MAX},{FLT_MAX,FLT_MAX,FLT_MAX,FLT_MAX}};
  int   ti[2][4] = {{INT_MAX,INT_MAX,INT_MAX,INT_MAX},{INT_MAX,INT_MAX,INT_MAX,INT_MAX}};

  // ---- Af/Bf per-lane LDS offsets, loop-invariant parts ----------------
  int offA[4];
#pragma unroll
  for (int ni = 0; ni < 4; ++ni){
    const int arow = wc*64 + ni*16 + r16;
    const int xa = (arow & 3) ^ ((arow >> 2) & 3);
    offA[ni] = arow*32 + ((quad ^ xa) << 3);
  }

  __syncthreads();   // tile 0 drained; Bs complete

  for (int i = 0; i < 32; ++i){
    const int ct = i >> 3, kt = i & 7;

    // ---- read fragments of tile i (As holds tile i) --------------------
    bf16x8 Bf[2], Af[4];
#pragma unroll
    for (int mi = 0; mi < 2; ++mi){
      const int row = wr*32 + mi*16 + r16;
      Bf[mi] = *reinterpret_cast<const bf16x8*>(
          &Bs[row*256 + (((kt*4 + quad) ^ (row & 7)) << 3)]);
    }
#pragma unroll
    for (int ni = 0; ni < 4; ++ni)
      Af[ni] = *reinterpret_cast<const bf16x8*>(&As[offA[ni]]);

    __syncthreads();                 // all reads done -> As overwrite safe
    if (i < 31) STAGE(i + 1)         // DMA in flight under MFMA below

#pragma unroll
    for (int ni = 0; ni < 4; ++ni){
      acc[0][ni] = __builtin_amdgcn_mfma_f32_16x16x32_bf16(Af[ni], Bf[0], acc[0][ni], 0, 0, 0);
      acc[1][ni] = __builtin_amdgcn_mfma_f32_16x16x32_bf16(Af[ni], Bf[1], acc[1][ni], 0, 0, 0);
    }

    if (kt == 7){
#pragma unroll
      for (int mi = 0; mi < 2; ++mi)
#pragma unroll
        for (int ni = 0; ni < 4; ++ni){
          const int c0 = ct*256 + wc*64 + ni*16 + quad*4;
          const float4 cn = *reinterpret_cast<const float4*>(cnx_l + c0);
          const f32x4 a = acc[mi][ni];
          ins4(ts[mi], ti[mi], cn.x - 2.f*a[0], c0+0);
          ins4(ts[mi], ti[mi], cn.y - 2.f*a[1], c0+1);
          ins4(ts[mi], ti[mi], cn.z - 2.f*a[2], c0+2);
          ins4(ts[mi], ti[mi], cn.w - 2.f*a[3], c0+3);
          acc[mi][ni] = (f32x4){0.f,0.f,0.f,0.f};
        }
    }
    __syncthreads();                 // DMA drained: As holds tile i+1
  }
#undef STAGE

  // ---- rowmin publish + list init (validated r12-r14) ------------------
#pragma unroll
  for (int mi = 0; mi < 2; ++mi){
    float m = ts[mi][0];
    m = fminf(m, __shfl_xor(m, 16));
    m = fminf(m, __shfl_xor(m, 32));
    if (quad == 0) rowm[(wr*32 + mi*16 + r16)*4 + wc] = m;
  }
  if (tid < 64){ cnt_l[tid] = 0; ovf_l[tid] = 0; }
  __syncthreads();

  // ---- per-lane margin emission (lane-overflow -> hard) -----------------
#pragma unroll
  for (int mi = 0; mi < 2; ++mi){
    const int row = wr*32 + mi*16 + r16;
    const float m1 = fminf(fminf(rowm[row*4], rowm[row*4+1]),
                           fminf(rowm[row*4+2], rowm[row*4+3]));
    const float thr = m1 + AMB;
#pragma unroll
    for (int e = 0; e < 4; ++e){
      if (ts[mi][e] <= thr){
        const int pos = atomicAdd(&cnt_l[row], 1);
        if (pos < 16) cand_l[row*16 + pos] = ti[mi][e];
      }
    }
    if (ts[mi][3] <= thr) ovf_l[row] = 1;   // lane may have dropped entries
  }
  __syncthreads();

  // ---- classify & emit --------------------------------------------------
  int apos = -1, hpos = -1, myc = 0;
  if (tid < 64){
    myc = cnt_l[tid];
    if (!ovf_l[tid] && myc == 1){
      idxw[LVL * NROWS + rowbase + tid] = cand_l[tid*16];
    } else if (!ovf_l[tid] && myc <= 16){
      apos = atomicAdd(&acnt_s, 1);
    } else {
      hpos = atomicAdd(&hcnt_s, 1);
    }
  }
  __syncthreads();
  if (tid == 0){
    abase_s = acnt_s ? atomicAdd(&cnt8[LVL], acnt_s) : 0;
    hbase_s = hcnt_s ? atomicAdd(&cnt8[4 + LVL], hcnt_s) : 0;
  }
  __syncthreads();
  if (apos >= 0){
    int* rp = arecs + (size_t)(abase_s + apos) * REC;
    rp[0] = rowbase + tid; rp[1] = myc;
    for (int e = 0; e < myc; ++e) rp[2+e] = cand_l[tid*16 + e];
  }
  if (hpos >= 0) hrows[hbase_s + hpos] = rowbase + tid;
}

// ---------------- K2a: amb rows (verbatim r12-r14, validated) -----------
template<int LVL>
__global__ __launch_bounds__(256)
void rvq_amb(const float* __restrict__ feat,
             const float* __restrict__ cb32,
             const float* __restrict__ cnx_l,
             int* __restrict__ idxw,
             const int* __restrict__ cnt8,
             const int* __restrict__ arecs)
{
  __shared__ float rres[16][260];
  const int tid = threadIdx.x;
  const int g = tid >> 4, q = tid & 15;
  const int cnt = cnt8[LVL];
  const float* cbl = cb32 + (size_t)LVL * KC * DIM;

  for (int rr = blockIdx.x * 16 + g; rr < cnt; rr += gridDim.x * 16){
    const int* rp = arecs + (size_t)rr * REC;
    const int grow = rp[0];
    const int c = rp[1];

    float4 rv[4];
#pragma unroll
    for (int i4 = 0; i4 < 4; ++i4){
      const int d = q*16 + i4*4;
      float4 w = *reinterpret_cast<const float4*>(feat + (size_t)grow * DIM + d);
#pragma unroll
      for (int j2 = 0; j2 < LVL; ++j2){
        const int kj = idxw[(size_t)j2 * NROWS + grow];
        const float4 cv = *reinterpret_cast<const float4*>(
            cb32 + ((size_t)j2 * KC + kj) * DIM + d);
        w.x -= cv.x; w.y -= cv.y; w.z -= cv.z; w.w -= cv.w;
      }
      rv[i4] = w;
      *reinterpret_cast<float4*>(&rres[g][d]) = w;
    }

    float m1 = FLT_MAX, m2 = FLT_MAX; int i1 = INT_MAX;
    for (int qq = 0; qq < c; ++qq){
      const int ci = rp[2+qq];
      const float* cp = cbl + (size_t)ci * DIM + q*16;
      float pa = 0.f;
#pragma unroll
      for (int j = 0; j < 4; ++j){
        const float4 cv = *reinterpret_cast<const float4*>(cp + j*4);
        pa = fmaf(rv[j].x, cv.x, pa); pa = fmaf(rv[j].y, cv.y, pa);
        pa = fmaf(rv[j].z, cv.z, pa); pa = fmaf(rv[j].w, cv.w, pa);
      }
#pragma unroll
      for (int m = 1; m < 16; m <<= 1) pa += __shfl_xor(pa, m);
      const float sc = cnx_l[ci] - 2.0f * pa;
      if (sless(sc, ci, m1, i1)){ m2 = m1; m1 = sc; i1 = ci; }
      else m2 = fminf(m2, sc);
    }

    int winner = i1;
    if (!(m2 - m1 > GUARD)){
      float bs = FLT_MAX; int bi = INT_MAX;
      for (int k = q; k < c; k += 16){
        const int ci = rp[2+k];
        float a = 0.f;
        for (int d4 = 0; d4 < 64; ++d4){
          const float4 cv = *reinterpret_cast<const float4*>(cbl + (size_t)ci * DIM + d4*4);
          const float4 rw = *reinterpret_cast<const float4*>(&rres[g][d4*4]);
          a = fmaf(rw.x, cv.x, a); a = fmaf(rw.y, cv.y, a);
          a = fmaf(rw.z, cv.z, a); a = fmaf(rw.w, cv.w, a);
        }
        const float sc = cnx_l[ci] - 2.0f * a;
        if (sless(sc, ci, bs, bi)){ bs = sc; bi = ci; }
      }
#pragma unroll
      for (int m = 1; m < 16; m <<= 1){
        const float ob = __shfl_xor(bs, m); const int oi = __shfl_xor(bi, m);
        if (sless(ob, oi, bs, bi)){ bs = ob; bi = oi; }
      }
      winner = bi;
    }
    if (q == 0) idxw[(size_t)LVL * NROWS + grow] = winner;
  }
}

// ---------------- K2b: hard rows (verbatim r11-r14, validated) ----------
template<int LVL>
__global__ __launch_bounds__(256)
void rvq_hard(const float* __restrict__ feat,
              const float* __restrict__ cb32,
              const float* __restrict__ cnx_l,
              int* __restrict__ idxw,
              const int* __restrict__ cnt8,
              const int* __restrict__ hrows)
{
  __shared__ float rres[260];
  __shared__ float scb[1024];
  __shared__ float wmn[4];
  __shared__ float wbs[4];
  __shared__ int   wbi[4];
  const int tid = threadIdx.x;
  const int g = tid >> 4, q = tid & 15;
  const int wv = tid >> 6, ln = tid & 63;
  const int cnt = cnt8[4 + LVL];
  const float* cbl = cb32 + (size_t)LVL * KC * DIM;

  for (int r = blockIdx.x; r < cnt; r += gridDim.x){
    const int grow = hrows[r];
    if (tid < 16){
#pragma unroll
      for (int i4 = 0; i4 < 4; ++i4){
        const int d = tid*16 + i4*4;
        float4 w = *reinterpret_cast<const float4*>(feat + (size_t)grow * DIM + d);
#pragma unroll
        for (int j2 = 0; j2 < LVL; ++j2){
          const int kj = idxw[(size_t)j2 * NROWS + grow];
          const float4 cv = *reinterpret_cast<const float4*>(
              cb32 + ((size_t)j2 * KC + kj) * DIM + d);
          w.x -= cv.x; w.y -= cv.y; w.z -= cv.z; w.w -= cv.w;
        }
        *reinterpret_cast<float4*>(&rres[d]) = w;
      }
    }
    __syncthreads();

    float4 rv[4];
#pragma unroll
    for (int j = 0; j < 4; ++j)
      rv[j] = *reinterpret_cast<const float4*>(&rres[q*16 + j*4]);

    for (int t = 0; t < 64; ++t){
      const int ci = g*64 + t;
      float pa = 0.f;
#pragma unroll
      for (int j = 0; j < 4; ++j){
        const float4 cv = *reinterpret_cast<const float4*>(
            cbl + (size_t)ci * DIM + q*16 + j*4);
        pa = fmaf(rv[j].x, cv.x, pa); pa = fmaf(rv[j].y, cv.y, pa);
        pa = fmaf(rv[j].z, cv.z, pa); pa = fmaf(rv[j].w, cv.w, pa);
      }
#pragma unroll
      for (int m = 1; m < 16; m <<= 1) pa += __shfl_xor(pa, m);
      if (q == 0) scb[ci] = cnx_l[ci] - 2.0f * pa;
    }
    __syncthreads();

    float mn = fminf(fminf(scb[tid], scb[tid+256]), fminf(scb[tid+512], scb[tid+768]));
#pragma unroll
    for (int m = 1; m < 64; m <<= 1) mn = fminf(mn, __shfl_xor(mn, m));
    if (ln == 0) wmn[wv] = mn;
    __syncthreads();
    const float m1p = fminf(fminf(wmn[0], wmn[1]), fminf(wmn[2], wmn[3]));
    const float thr = m1p + GUARD;

    float bs = FLT_MAX; int bi = INT_MAX;
#pragma unroll
    for (int k = 0; k < 4; ++k){
      const int ci = tid + k*256;
      if (scb[ci] <= thr){
        float a = 0.f;
        for (int d4 = 0; d4 < 64; ++d4){
          const float4 cv = *reinterpret_cast<const float4*>(cbl + (size_t)ci * DIM + d4*4);
          const float4 rw = *reinterpret_cast<const float4*>(&rres[d4*4]);
          a = fmaf(rw.x, cv.x, a); a = fmaf(rw.y, cv.y, a);
          a = fmaf(rw.z, cv.z, a); a = fmaf(rw.w, cv.w, a);
        }
        const float sc = cnx_l[ci] - 2.0f * a;
        if (sless(sc, ci, bs, bi)){ bs = sc; bi = ci; }
      }
    }
#pragma unroll
    for (int m = 1; m < 64; m <<= 1){
      const float ob = __shfl_xor(bs, m); const int oi = __shfl_xor(bi, m);
      if (sless(ob, oi, bs, bi)){ bs = ob; bi = oi; }
    }
    if (ln == 0){ wbs[wv] = bs; wbi[wv] = bi; }
    __syncthreads();
    if (tid == 0){
      float fb = wbs[0]; int fi = wbi[0];
#pragma unroll
      for (int w = 1; w < 4; ++w)
        if (sless(wbs[w], wbi[w], fb, fi)){ fb = wbs[w]; fi = wbi[w]; }
      idxw[(size_t)LVL * NROWS + grow] = fi;
    }
    __syncthreads();
  }
}

// ---------------- K3: final output = q0+q1+q2+q3 (validated r5-r14) -----
__global__ __launch_bounds__(256)
void rvq_out(const float* __restrict__ cb32,
             const int* __restrict__ idxw,
             float* __restrict__ out)
{
  const int tid = threadIdx.x;
  const int row = tid >> 4, sub = tid & 15;
  const size_t n = (size_t)blockIdx.x * 16 + row;
  int hist[NLVL];
#pragma unroll
  for (int j2 = 0; j2 < 4; ++j2) hist[j2] = idxw[(size_t)j2 * NROWS + n];
#pragma unroll
  for (int i = 0; i < 4; ++i){
    const int d = sub*4 + i*64;
    float4 a = *reinterpret_cast<const float4*>(
        cb32 + ((size_t)0 * KC + hist[0]) * DIM + d);
#pragma unroll
    for (int j2 = 1; j2 < 4; ++j2){
      const float4 qv = *reinterpret_cast<const float4*>(
          cb32 + ((size_t)j2 * KC + hist[j2]) * DIM + d);
      a.x += qv.x; a.y += qv.y; a.z += qv.z; a.w += qv.w;
    }
    *reinterpret_cast<float4*>(out + n*DIM + d) = a;
  }
}

extern "C" void kernel_launch(void* const* d_in, const int* in_sizes, int n_in,
                              void* d_out, int out_size, void* d_ws, size_t ws_size,
                              hipStream_t stream){
  const float* feat = (const float*)d_in[0];
  const float* cb32 = (const float*)d_in[1];
  float* out = (float*)d_out;

  char* ws = (char*)d_ws;
  float* cnx  = (float*)(ws);                              // 16 KB
  int*   cnt8 = (int*)(ws + 16384);                        // 8 counters
  unsigned short* cbb = (unsigned short*)(ws + 32768);     // 2 MB
  int*   idxw = (int*)(ws + 32768 + 2097152);              // 2 MB
  int*   arecs = (int*)(ws + 32768 + 2097152 + 2097152);   // 9.5 MB
  int*   hrows = (int*)(ws + 32768 + 2097152 + 2097152 + 9961472); // 512 KB

  zero8<<<1, 64, 0, stream>>>(cnt8);
  prep_cbb<<<1024, 256, 0, stream>>>(cb32, cbb);
  prep_cn<<<64, 64, 0, stream>>>(cb32, cnx);

#define LVL_STEP(L) \
  rvq_score<L><<<2048, 512, 0, stream>>>(feat, cb32, cbb + (size_t)L*KC*DIM, \
      cnx + L*KC, idxw, cnt8, arecs, hrows); \
  rvq_amb<L><<<2048, 256, 0, stream>>>(feat, cb32, cnx + L*KC, idxw, cnt8, arecs); \
  rvq_hard<L><<<512, 256, 0, stream>>>(feat, cb32, cnx + L*KC, idxw, cnt8, hrows);

  LVL_STEP(0)
  LVL_STEP(1)
  LVL_STEP(2)
  LVL_STEP(3)
#undef LVL_STEP

  rvq_out<<<8192, 256, 0, stream>>>(cb32, idxw, out);
}

// Round 17
// 1126.531 us; speedup vs baseline: 1.0225x; 1.0064x over previous
//
#include <hip/hip_runtime.h>
#include <hip/hip_bf16.h>
#include <float.h>
#include <limits.h>

#define NROWS 131072
#define DIM   256
#define NLVL  4
#define KC    1024
#define AMB   6.0f     // bf16-score ambiguity margin (validated r4-r16)
#define GUARD 0.25f    // parallel-vs-serial fp32 ordering guard (validated r10-r16)
#define REC   18       // amb record: row, cnt, cand[16]

typedef __attribute__((ext_vector_type(8))) short bf16x8;
typedef __attribute__((ext_vector_type(4))) float f32x4;
typedef __attribute__((ext_vector_type(4))) unsigned short us4;

__device__ __forceinline__ unsigned short f2b(float f){
  __hip_bfloat16 h = __float2bfloat16(f);
  return *reinterpret_cast<unsigned short*>(&h);
}

__device__ __forceinline__ float sqb(float x){
  float s = x * x;
  asm volatile("" : "+v"(s));
  return s;
}

__device__ __forceinline__ bool sless(float a, int ia, float b, int ib){
  return a < b || (a == b && ia < ib);
}

// async global->LDS 16B (DMA; LDS dest is wave-uniform base + lane*16)
__device__ __forceinline__ void gld16(const unsigned short* g, unsigned short* l){
  __builtin_amdgcn_global_load_lds(
      (const __attribute__((address_space(1))) unsigned int*)g,
      (__attribute__((address_space(3))) unsigned int*)l, 16, 0, 0);
}

// strict-< top-4 insert (tie-correct for ascending-index per-lane streams)
__device__ __forceinline__ void ins4(float (&s)[4], int (&ix)[4], float v, int ci){
  if (v < s[3]){
    s[3]=v; ix[3]=ci;
#pragma unroll
    for (int j = 3; j >= 1; --j){
      if (s[j] < s[j-1]){
        float t=s[j-1]; s[j-1]=s[j]; s[j]=t;
        int u=ix[j-1]; ix[j-1]=ix[j]; ix[j]=u;
      }
    }
  }
}

// ---------------- prep kernels (validated r4-r16) -----------------------
__global__ void zero8(int* __restrict__ p){
  if (threadIdx.x < 8) p[threadIdx.x] = 0;
}

__global__ void prep_cbb(const float* __restrict__ cb, unsigned short* __restrict__ cbb){
  const int wave = threadIdx.x >> 6, lane = threadIdx.x & 63;
  const int c = blockIdx.x * 4 + wave;
  const size_t off = (size_t)c * DIM + lane * 4;
  const float4 v = *reinterpret_cast<const float4*>(cb + off);
  us4 u = { f2b(v.x), f2b(v.y), f2b(v.z), f2b(v.w) };
  *reinterpret_cast<us4*>(cbb + off) = u;
}

__global__ void prep_cn(const float* __restrict__ cb, float* __restrict__ cnx){
  const int c = blockIdx.x * 64 + threadIdx.x;
  const float* p = cb + (size_t)c * DIM;
  float blk[2];
  for (int b = 0; b < 2; ++b){
    float r[8];
#pragma unroll
    for (int j = 0; j < 8; ++j) r[j] = sqb(p[b*128 + j]);
    for (int i = 8; i < 128; i += 8)
#pragma unroll
      for (int j = 0; j < 8; ++j) r[j] += sqb(p[b*128 + i + j]);
    blk[b] = ((r[0]+r[1]) + (r[2]+r[3])) + ((r[4]+r[5]) + (r[6]+r[7]));
  }
  cnx[c] = blk[0] + blk[1];
}

// ---------------- K1: LDS-tiled GEMM + lane-top4 classify ---------------
// r16 verbatim + (a) cnx prefetch at kt==0 (epilogue stall removed),
// (b) decomposed Bf offset: bB + ((kt^bx)<<5) — fewer VALU, shorter chain.
template<int LVL>
__global__ __launch_bounds__(512, 4)
void rvq_score(const float* __restrict__ feat,
               const float* __restrict__ cb32,
               const unsigned short* __restrict__ cbb_l,
               const float* __restrict__ cnx_l,
               int* __restrict__ idxw,
               int* __restrict__ cnt8,      // [0..3] amb, [4..7] hard
               int* __restrict__ arecs,     // [*][REC]
               int* __restrict__ hrows)
{
  __shared__ __align__(16) char smem[49664];
  unsigned short* Bs = (unsigned short*)smem;            // 32 KB
  unsigned short* As = (unsigned short*)(smem + 32768);  // 16 KB (single buf, linear)
  // aliases into As region (dead after main loop):
  float* rowm  = (float*)(smem + 32768);                 // [64*4]
  int*   cnt_l = (int*)(smem + 32768 + 1024);            // [64]
  int*   ovf_l = (int*)(smem + 32768 + 1280);            // [64]
  int*   cand_l= (int*)(smem + 32768 + 1536);            // [64*16]
  __shared__ int acnt_s, hcnt_s, abase_s, hbase_s;

  const int tid  = threadIdx.x;
  const int lane = tid & 63;
  const int wave = tid >> 6;
  const int r16  = lane & 15, quad = lane >> 4;
  const int wr   = wave >> 2, wc = wave & 3;
  const int rowbase = (int)blockIdx.x * 64;

  if (tid == 0){ acnt_s = 0; hcnt_s = 0; }

  // ---- per-thread staging constants (slot i -> (r,c); src chunk = c^x(r))
  const int i0 = tid,        r0 = i0 >> 2, c0i = i0 & 3;
  const int i1 = 512 + tid,  r1 = i1 >> 2, c1i = i1 & 3;
  const int x0 = (r0 & 3) ^ ((r0 >> 2) & 3);
  const int x1 = (r1 & 3) ^ ((r1 >> 2) & 3);
  const size_t gbase0 = (size_t)r0 * DIM + ((c0i ^ x0) << 3);
  const size_t gbase1 = (size_t)r1 * DIM + ((c1i ^ x1) << 3);
  unsigned short* ldst0 = As + i0 * 8;    // byte off i0*16
  unsigned short* ldst1 = As + i1 * 8;

#define STAGE(TI) { \
    const size_t toff = (size_t)((TI) >> 3) * (256*DIM) + ((TI) & 7) * 32; \
    gld16(cbb_l + gbase0 + toff, ldst0); \
    gld16(cbb_l + gbase1 + toff, ldst1); \
  }

  // prologue: tile 0 in flight during B build
  STAGE(0)

  // ---- phase 0: residual rows -> LDS (exact fp32 chain -> bf16) --------
  {
    const int row = tid >> 3;
    const int d0 = (tid & 7) * 32;
    const int grow = rowbase + row;
    int hist[NLVL > 1 ? NLVL : 1];
#pragma unroll
    for (int j = 0; j < LVL; ++j) hist[j] = idxw[j * NROWS + grow];
#pragma unroll
    for (int c4 = 0; c4 < 4; ++c4){
      const int d = d0 + c4*8;
      const float* p = feat + (size_t)grow * DIM + d;
      float4 f0 = *reinterpret_cast<const float4*>(p);
      float4 f1 = *reinterpret_cast<const float4*>(p + 4);
#pragma unroll
      for (int j = 0; j < LVL; ++j){
        const float* cp = cb32 + ((size_t)j * KC + hist[j]) * DIM + d;
        const float4 c0 = *reinterpret_cast<const float4*>(cp);
        const float4 c1 = *reinterpret_cast<const float4*>(cp + 4);
        f0.x -= c0.x; f0.y -= c0.y; f0.z -= c0.z; f0.w -= c0.w;
        f1.x -= c1.x; f1.y -= c1.y; f1.z -= c1.z; f1.w -= c1.w;
      }
      bf16x8 b;
      b[0]=(short)f2b(f0.x); b[1]=(short)f2b(f0.y); b[2]=(short)f2b(f0.z); b[3]=(short)f2b(f0.w);
      b[4]=(short)f2b(f1.x); b[5]=(short)f2b(f1.y); b[6]=(short)f2b(f1.z); b[7]=(short)f2b(f1.w);
      *reinterpret_cast<bf16x8*>(&Bs[row*256 + (((d >> 3) ^ (row & 7)) << 3)]) = b;
    }
  }

  f32x4 acc[2][4];
#pragma unroll
  for (int mi = 0; mi < 2; ++mi)
#pragma unroll
    for (int ni = 0; ni < 4; ++ni) acc[mi][ni] = (f32x4){0.f,0.f,0.f,0.f};

  float ts[2][4] = {{FLT_MAX,FLT_MAX,FLT_MAX,FLT_MAX},{FLT_MAX,FLT_MAX,FLT_MAX,FLT_MAX}};
  int   ti[2][4] = {{INT_MAX,INT_MAX,INT_MAX,INT_MAX},{INT_MAX,INT_MAX,INT_MAX,INT_MAX}};

  // ---- per-lane LDS offsets, loop-invariant parts ----------------------
  int offA[4];
#pragma unroll
  for (int ni = 0; ni < 4; ++ni){
    const int arow = wc*64 + ni*16 + r16;
    const int xa = (arow & 3) ^ ((arow >> 2) & 3);
    offA[ni] = arow*32 + ((quad ^ xa) << 3);
  }
  // Bf offset decomposition: off(kt) = bB[mi] + ((kt ^ bx[mi]) << 5)
  int bB[2], bx[2];
#pragma unroll
  for (int mi = 0; mi < 2; ++mi){
    const int row = wr*32 + mi*16 + r16;
    const int rx = row & 7;
    bx[mi] = rx >> 2;
    bB[mi] = row*256 + ((quad ^ (rx & 3)) << 3);
  }

  float4 cnp[4];   // prefetched ||c||^2 for current ct (filled at kt==0)

  __syncthreads();   // tile 0 drained; Bs complete

  for (int i = 0; i < 32; ++i){
    const int ct = i >> 3, kt = i & 7;

    // prefetch this ct's cn values early (consumed at kt==7)
    if (kt == 0){
      const int cb = ct*256 + wc*64 + quad*4;
      cnp[0] = *reinterpret_cast<const float4*>(cnx_l + cb);
      cnp[1] = *reinterpret_cast<const float4*>(cnx_l + cb + 16);
      cnp[2] = *reinterpret_cast<const float4*>(cnx_l + cb + 32);
      cnp[3] = *reinterpret_cast<const float4*>(cnx_l + cb + 48);
    }

    // ---- read fragments of tile i (As holds tile i) --------------------
    bf16x8 Bf[2], Af[4];
#pragma unroll
    for (int mi = 0; mi < 2; ++mi)
      Bf[mi] = *reinterpret_cast<const bf16x8*>(
          &Bs[bB[mi] + ((kt ^ bx[mi]) << 5)]);
#pragma unroll
    for (int ni = 0; ni < 4; ++ni)
      Af[ni] = *reinterpret_cast<const bf16x8*>(&As[offA[ni]]);

    __syncthreads();                 // all reads done -> As overwrite safe
    if (i < 31) STAGE(i + 1)         // DMA in flight under MFMA below

#pragma unroll
    for (int ni = 0; ni < 4; ++ni){
      acc[0][ni] = __builtin_amdgcn_mfma_f32_16x16x32_bf16(Af[ni], Bf[0], acc[0][ni], 0, 0, 0);
      acc[1][ni] = __builtin_amdgcn_mfma_f32_16x16x32_bf16(Af[ni], Bf[1], acc[1][ni], 0, 0, 0);
    }

    if (kt == 7){
#pragma unroll
      for (int mi = 0; mi < 2; ++mi)
#pragma unroll
        for (int ni = 0; ni < 4; ++ni){
          const int c0 = ct*256 + wc*64 + ni*16 + quad*4;
          const float4 cn = cnp[ni];
          const f32x4 a = acc[mi][ni];
          ins4(ts[mi], ti[mi], cn.x - 2.f*a[0], c0+0);
          ins4(ts[mi], ti[mi], cn.y - 2.f*a[1], c0+1);
          ins4(ts[mi], ti[mi], cn.z - 2.f*a[2], c0+2);
          ins4(ts[mi], ti[mi], cn.w - 2.f*a[3], c0+3);
          acc[mi][ni] = (f32x4){0.f,0.f,0.f,0.f};
        }
    }
    __syncthreads();                 // DMA drained: As holds tile i+1
  }
#undef STAGE

  // ---- rowmin publish + list init (validated r12-r16) ------------------
#pragma unroll
  for (int mi = 0; mi < 2; ++mi){
    float m = ts[mi][0];
    m = fminf(m, __shfl_xor(m, 16));
    m = fminf(m, __shfl_xor(m, 32));
    if (quad == 0) rowm[(wr*32 + mi*16 + r16)*4 + wc] = m;
  }
  if (tid < 64){ cnt_l[tid] = 0; ovf_l[tid] = 0; }
  __syncthreads();

  // ---- per-lane margin emission (lane-overflow -> hard) -----------------
#pragma unroll
  for (int mi = 0; mi < 2; ++mi){
    const int row = wr*32 + mi*16 + r16;
    const float m1 = fminf(fminf(rowm[row*4], rowm[row*4+1]),
                           fminf(rowm[row*4+2], rowm[row*4+3]));
    const float thr = m1 + AMB;
#pragma unroll
    for (int e = 0; e < 4; ++e){
      if (ts[mi][e] <= thr){
        const int pos = atomicAdd(&cnt_l[row], 1);
        if (pos < 16) cand_l[row*16 + pos] = ti[mi][e];
      }
    }
    if (ts[mi][3] <= thr) ovf_l[row] = 1;   // lane may have dropped entries
  }
  __syncthreads();

  // ---- classify & emit --------------------------------------------------
  int apos = -1, hpos = -1, myc = 0;
  if (tid < 64){
    myc = cnt_l[tid];
    if (!ovf_l[tid] && myc == 1){
      idxw[LVL * NROWS + rowbase + tid] = cand_l[tid*16];
    } else if (!ovf_l[tid] && myc <= 16){
      apos = atomicAdd(&acnt_s, 1);
    } else {
      hpos = atomicAdd(&hcnt_s, 1);
    }
  }
  __syncthreads();
  if (tid == 0){
    abase_s = acnt_s ? atomicAdd(&cnt8[LVL], acnt_s) : 0;
    hbase_s = hcnt_s ? atomicAdd(&cnt8[4 + LVL], hcnt_s) : 0;
  }
  __syncthreads();
  if (apos >= 0){
    int* rp = arecs + (size_t)(abase_s + apos) * REC;
    rp[0] = rowbase + tid; rp[1] = myc;
    for (int e = 0; e < myc; ++e) rp[2+e] = cand_l[tid*16 + e];
  }
  if (hpos >= 0) hrows[hbase_s + hpos] = rowbase + tid;
}

// ---------------- K2a: amb rows (verbatim r12-r16, validated) -----------
template<int LVL>
__global__ __launch_bounds__(256)
void rvq_amb(const float* __restrict__ feat,
             const float* __restrict__ cb32,
             const float* __restrict__ cnx_l,
             int* __restrict__ idxw,
             const int* __restrict__ cnt8,
             const int* __restrict__ arecs)
{
  __shared__ float rres[16][260];
  const int tid = threadIdx.x;
  const int g = tid >> 4, q = tid & 15;
  const int cnt = cnt8[LVL];
  const float* cbl = cb32 + (size_t)LVL * KC * DIM;

  for (int rr = blockIdx.x * 16 + g; rr < cnt; rr += gridDim.x * 16){
    const int* rp = arecs + (size_t)rr * REC;
    const int grow = rp[0];
    const int c = rp[1];

    float4 rv[4];
#pragma unroll
    for (int i4 = 0; i4 < 4; ++i4){
      const int d = q*16 + i4*4;
      float4 w = *reinterpret_cast<const float4*>(feat + (size_t)grow * DIM + d);
#pragma unroll
      for (int j2 = 0; j2 < LVL; ++j2){
        const int kj = idxw[(size_t)j2 * NROWS + grow];
        const float4 cv = *reinterpret_cast<const float4*>(
            cb32 + ((size_t)j2 * KC + kj) * DIM + d);
        w.x -= cv.x; w.y -= cv.y; w.z -= cv.z; w.w -= cv.w;
      }
      rv[i4] = w;
      *reinterpret_cast<float4*>(&rres[g][d]) = w;
    }

    float m1 = FLT_MAX, m2 = FLT_MAX; int i1 = INT_MAX;
    for (int qq = 0; qq < c; ++qq){
      const int ci = rp[2+qq];
      const float* cp = cbl + (size_t)ci * DIM + q*16;
      float pa = 0.f;
#pragma unroll
      for (int j = 0; j < 4; ++j){
        const float4 cv = *reinterpret_cast<const float4*>(cp + j*4);
        pa = fmaf(rv[j].x, cv.x, pa); pa = fmaf(rv[j].y, cv.y, pa);
        pa = fmaf(rv[j].z, cv.z, pa); pa = fmaf(rv[j].w, cv.w, pa);
      }
#pragma unroll
      for (int m = 1; m < 16; m <<= 1) pa += __shfl_xor(pa, m);
      const float sc = cnx_l[ci] - 2.0f * pa;
      if (sless(sc, ci, m1, i1)){ m2 = m1; m1 = sc; i1 = ci; }
      else m2 = fminf(m2, sc);
    }

    int winner = i1;
    if (!(m2 - m1 > GUARD)){
      float bs = FLT_MAX; int bi = INT_MAX;
      for (int k = q; k < c; k += 16){
        const int ci = rp[2+k];
        float a = 0.f;
        for (int d4 = 0; d4 < 64; ++d4){
          const float4 cv = *reinterpret_cast<const float4*>(cbl + (size_t)ci * DIM + d4*4);
          const float4 rw = *reinterpret_cast<const float4*>(&rres[g][d4*4]);
          a = fmaf(rw.x, cv.x, a); a = fmaf(rw.y, cv.y, a);
          a = fmaf(rw.z, cv.z, a); a = fmaf(rw.w, cv.w, a);
        }
        const float sc = cnx_l[ci] - 2.0f * a;
        if (sless(sc, ci, bs, bi)){ bs = sc; bi = ci; }
      }
#pragma unroll
      for (int m = 1; m < 16; m <<= 1){
        const float ob = __shfl_xor(bs, m); const int oi = __shfl_xor(bi, m);
        if (sless(ob, oi, bs, bi)){ bs = ob; bi = oi; }
      }
      winner = bi;
    }
    if (q == 0) idxw[(size_t)LVL * NROWS + grow] = winner;
  }
}

// ---------------- K2b: hard rows (verbatim r11-r16, validated) ----------
template<int LVL>
__global__ __launch_bounds__(256)
void rvq_hard(const float* __restrict__ feat,
              const float* __restrict__ cb32,
              const float* __restrict__ cnx_l,
              int* __restrict__ idxw,
              const int* __restrict__ cnt8,
              const int* __restrict__ hrows)
{
  __shared__ float rres[260];
  __shared__ float scb[1024];
  __shared__ float wmn[4];
  __shared__ float wbs[4];
  __shared__ int   wbi[4];
  const int tid = threadIdx.x;
  const int g = tid >> 4, q = tid & 15;
  const int wv = tid >> 6, ln = tid & 63;
  const int cnt = cnt8[4 + LVL];
  const float* cbl = cb32 + (size_t)LVL * KC * DIM;

  for (int r = blockIdx.x; r < cnt; r += gridDim.x){
    const int grow = hrows[r];
    if (tid < 16){
#pragma unroll
      for (int i4 = 0; i4 < 4; ++i4){
        const int d = tid*16 + i4*4;
        float4 w = *reinterpret_cast<const float4*>(feat + (size_t)grow * DIM + d);
#pragma unroll
        for (int j2 = 0; j2 < LVL; ++j2){
          const int kj = idxw[(size_t)j2 * NROWS + grow];
          const float4 cv = *reinterpret_cast<const float4*>(
              cb32 + ((size_t)j2 * KC + kj) * DIM + d);
          w.x -= cv.x; w.y -= cv.y; w.z -= cv.z; w.w -= cv.w;
        }
        *reinterpret_cast<float4*>(&rres[d]) = w;
      }
    }
    __syncthreads();

    float4 rv[4];
#pragma unroll
    for (int j = 0; j < 4; ++j)
      rv[j] = *reinterpret_cast<const float4*>(&rres[q*16 + j*4]);

    for (int t = 0; t < 64; ++t){
      const int ci = g*64 + t;
      float pa = 0.f;
#pragma unroll
      for (int j = 0; j < 4; ++j){
        const float4 cv = *reinterpret_cast<const float4*>(
            cbl + (size_t)ci * DIM + q*16 + j*4);
        pa = fmaf(rv[j].x, cv.x, pa); pa = fmaf(rv[j].y, cv.y, pa);
        pa = fmaf(rv[j].z, cv.z, pa); pa = fmaf(rv[j].w, cv.w, pa);
      }
#pragma unroll
      for (int m = 1; m < 16; m <<= 1) pa += __shfl_xor(pa, m);
      if (q == 0) scb[ci] = cnx_l[ci] - 2.0f * pa;
    }
    __syncthreads();

    float mn = fminf(fminf(scb[tid], scb[tid+256]), fminf(scb[tid+512], scb[tid+768]));
#pragma unroll
    for (int m = 1; m < 64; m <<= 1) mn = fminf(mn, __shfl_xor(mn, m));
    if (ln == 0) wmn[wv] = mn;
    __syncthreads();
    const float m1p = fminf(fminf(wmn[0], wmn[1]), fminf(wmn[2], wmn[3]));
    const float thr = m1p + GUARD;

    float bs = FLT_MAX; int bi = INT_MAX;
#pragma unroll
    for (int k = 0; k < 4; ++k){
      const int ci = tid + k*256;
      if (scb[ci] <= thr){
        float a = 0.f;
        for (int d4 = 0; d4 < 64; ++d4){
          const float4 cv = *reinterpret_cast<const float4*>(cbl + (size_t)ci * DIM + d4*4);
          const float4 rw = *reinterpret_cast<const float4*>(&rres[d4*4]);
          a = fmaf(rw.x, cv.x, a); a = fmaf(rw.y, cv.y, a);
          a = fmaf(rw.z, cv.z, a); a = fmaf(rw.w, cv.w, a);
        }
        const float sc = cnx_l[ci] - 2.0f * a;
        if (sless(sc, ci, bs, bi)){ bs = sc; bi = ci; }
      }
    }
#pragma unroll
    for (int m = 1; m < 64; m <<= 1){
      const float ob = __shfl_xor(bs, m); const int oi = __shfl_xor(bi, m);
      if (sless(ob, oi, bs, bi)){ bs = ob; bi = oi; }
    }
    if (ln == 0){ wbs[wv] = bs; wbi[wv] = bi; }
    __syncthreads();
    if (tid == 0){
      float fb = wbs[0]; int fi = wbi[0];
#pragma unroll
      for (int w = 1; w < 4; ++w)
        if (sless(wbs[w], wbi[w], fb, fi)){ fb = wbs[w]; fi = wbi[w]; }
      idxw[(size_t)LVL * NROWS + grow] = fi;
    }
    __syncthreads();
  }
}

// ---------------- K3: final output = q0+q1+q2+q3 (validated r5-r16) -----
__global__ __launch_bounds__(256)
void rvq_out(const float* __restrict__ cb32,
             const int* __restrict__ idxw,
             float* __restrict__ out)
{
  const int tid = threadIdx.x;
  const int row = tid >> 4, sub = tid & 15;
  const size_t n = (size_t)blockIdx.x * 16 + row;
  int hist[NLVL];
#pragma unroll
  for (int j2 = 0; j2 < 4; ++j2) hist[j2] = idxw[(size_t)j2 * NROWS + n];
#pragma unroll
  for (int i = 0; i < 4; ++i){
    const int d = sub*4 + i*64;
    float4 a = *reinterpret_cast<const float4*>(
        cb32 + ((size_t)0 * KC + hist[0]) * DIM + d);
#pragma unroll
    for (int j2 = 1; j2 < 4; ++j2){
      const float4 qv = *reinterpret_cast<const float4*>(
          cb32 + ((size_t)j2 * KC + hist[j2]) * DIM + d);
      a.x += qv.x; a.y += qv.y; a.z += qv.z; a.w += qv.w;
    }
    *reinterpret_cast<float4*>(out + n*DIM + d) = a;
  }
}

extern "C" void kernel_launch(void* const* d_in, const int* in_sizes, int n_in,
                              void* d_out, int out_size, void* d_ws, size_t ws_size,
                              hipStream_t stream){
  const float* feat = (const float*)d_in[0];
  const float* cb32 = (const float*)d_in[1];
  float* out = (float*)d_out;

  char* ws = (char*)d_ws;
  float* cnx  = (float*)(ws);                              // 16 KB
  int*   cnt8 = (int*)(ws + 16384);                        // 8 counters
  unsigned short* cbb = (unsigned short*)(ws + 32768);     // 2 MB
  int*   idxw = (int*)(ws + 32768 + 2097152);              // 2 MB
  int*   arecs = (int*)(ws + 32768 + 2097152 + 2097152);   // 9.5 MB
  int*   hrows = (int*)(ws + 32768 + 2097152 + 2097152 + 9961472); // 512 KB

  zero8<<<1, 64, 0, stream>>>(cnt8);
  prep_cbb<<<1024, 256, 0, stream>>>(cb32, cbb);
  prep_cn<<<64, 64, 0, stream>>>(cb32, cnx);

#define LVL_STEP(L) \
  rvq_score<L><<<2048, 512, 0, stream>>>(feat, cb32, cbb + (size_t)L*KC*DIM, \
      cnx + L*KC, idxw, cnt8, arecs, hrows); \
  rvq_amb<L><<<2048, 256, 0, stream>>>(feat, cb32, cnx + L*KC, idxw, cnt8, arecs); \
  rvq_hard<L><<<512, 256, 0, stream>>>(feat, cb32, cnx + L*KC, idxw, cnt8, hrows);

  LVL_STEP(0)
  LVL_STEP(1)
  LVL_STEP(2)
  LVL_STEP(3)
#undef LVL_STEP

  rvq_out<<<8192, 256, 0, stream>>>(cb32, idxw, out);
}

// Round 18
// 1027.039 us; speedup vs baseline: 1.1215x; 1.0969x over previous
//
#include <hip/hip_runtime.h>
#include <hip/hip_bf16.h>
#include <float.h>
#include <limits.h>

#define NROWS 131072
#define DIM   256
#define NLVL  4
#define KC    1024
#define AMB   6.0f     // bf16-score ambiguity margin (validated r4-r17)
#define GUARD 0.25f    // parallel-vs-serial fp32 ordering guard (validated r10-r17)
#define REC   18       // amb record: row, cnt, cand[16]

typedef __attribute__((ext_vector_type(8))) short bf16x8;
typedef __attribute__((ext_vector_type(4))) float f32x4;
typedef __attribute__((ext_vector_type(4))) unsigned short us4;

__device__ __forceinline__ unsigned short f2b(float f){
  __hip_bfloat16 h = __float2bfloat16(f);
  return *reinterpret_cast<unsigned short*>(&h);
}

__device__ __forceinline__ float sqb(float x){
  float s = x * x;
  asm volatile("" : "+v"(s));
  return s;
}

__device__ __forceinline__ bool sless(float a, int ia, float b, int ib){
  return a < b || (a == b && ia < ib);
}

// monotone float->u32 key with 10-bit center index embedded in the low bits.
// ordering = (score truncated to 2^-13 rel, index) lexicographic -> min key
// is first-index argmin of truncated scores. Truncation <= ~0.02 abs, far
// inside AMB slack; exactness preserved by the K2 exact-rescore machinery.
__device__ __forceinline__ unsigned fkey(float s, int ci){
  unsigned u = __builtin_bit_cast(unsigned, s);
  u ^= (unsigned)((int)u >> 31) | 0x80000000u;
  return (u & 0xFFFFFC00u) | (unsigned)ci;
}
__device__ __forceinline__ float fdec(unsigned k){
  const unsigned u = (k & 0x80000000u) ? (k ^ 0x80000000u) : ~k;
  return __builtin_bit_cast(float, u);
}

// branch-free keep-4-smallest insert (7 min/max ops on u32 keys)
__device__ __forceinline__ void ins4u(unsigned (&s)[4], unsigned k){
  s[3] = s[3] < k ? s[3] : k;
#pragma unroll
  for (int j = 3; j >= 1; --j){
    const unsigned lo = s[j-1] < s[j] ? s[j-1] : s[j];
    const unsigned hi = s[j-1] < s[j] ? s[j] : s[j-1];
    s[j-1] = lo; s[j] = hi;
  }
}

// ---------------- prep kernels (validated r4-r17) -----------------------
__global__ void zero8(int* __restrict__ p){
  if (threadIdx.x < 8) p[threadIdx.x] = 0;
}

__global__ void prep_cbb(const float* __restrict__ cb, unsigned short* __restrict__ cbb){
  const int wave = threadIdx.x >> 6, lane = threadIdx.x & 63;
  const int c = blockIdx.x * 4 + wave;
  const size_t off = (size_t)c * DIM + lane * 4;
  const float4 v = *reinterpret_cast<const float4*>(cb + off);
  us4 u = { f2b(v.x), f2b(v.y), f2b(v.z), f2b(v.w) };
  *reinterpret_cast<us4*>(cbb + off) = u;
}

__global__ void prep_cn(const float* __restrict__ cb, float* __restrict__ cnx){
  const int c = blockIdx.x * 64 + threadIdx.x;
  const float* p = cb + (size_t)c * DIM;
  float blk[2];
  for (int b = 0; b < 2; ++b){
    float r[8];
#pragma unroll
    for (int j = 0; j < 8; ++j) r[j] = sqb(p[b*128 + j]);
    for (int i = 8; i < 128; i += 8)
#pragma unroll
      for (int j = 0; j < 8; ++j) r[j] += sqb(p[b*128 + i + j]);
    blk[b] = ((r[0]+r[1]) + (r[2]+r[3])) + ((r[4]+r[5]) + (r[6]+r[7]));
  }
  cnx[c] = blk[0] + blk[1];
}

// ---------------- K1: LDS-tiled GEMM + u32-key lane-top4 classify -------
// r16 structure verbatim; selection arithmetic swapped to u32 keys
// (index-embedded, branch-free sort network) — semantics unchanged.
template<int LVL>
__global__ __launch_bounds__(512, 4)
void rvq_score(const float* __restrict__ feat,
               const float* __restrict__ cb32,
               const unsigned short* __restrict__ cbb_l,
               const float* __restrict__ cnx_l,
               int* __restrict__ idxw,
               int* __restrict__ cnt8,      // [0..3] amb, [4..7] hard
               int* __restrict__ arecs,     // [*][REC]
               int* __restrict__ hrows)
{
  __shared__ __align__(16) char smem[49664];
  unsigned short* Bs = (unsigned short*)smem;            // 32 KB
  unsigned short* As = (unsigned short*)(smem + 32768);  // 16 KB (single buf, linear)
  // aliases into As region (dead after main loop):
  unsigned* rowm = (unsigned*)(smem + 32768);            // [64*4]
  int*   cnt_l = (int*)(smem + 32768 + 1024);            // [64]
  int*   ovf_l = (int*)(smem + 32768 + 1280);            // [64]
  int*   cand_l= (int*)(smem + 32768 + 1536);            // [64*16]
  __shared__ int acnt_s, hcnt_s, abase_s, hbase_s;

  const int tid  = threadIdx.x;
  const int lane = tid & 63;
  const int wave = tid >> 6;
  const int r16  = lane & 15, quad = lane >> 4;
  const int wr   = wave >> 2, wc = wave & 3;
  const int rowbase = (int)blockIdx.x * 64;

  if (tid == 0){ acnt_s = 0; hcnt_s = 0; }

  // ---- per-thread staging constants (slot i -> (r,c); src chunk = c^x(r))
  const int i0 = tid,        r0 = i0 >> 2, c0i = i0 & 3;
  const int i1 = 512 + tid,  r1 = i1 >> 2, c1i = i1 & 3;
  const int x0 = (r0 & 3) ^ ((r0 >> 2) & 3);
  const int x1 = (r1 & 3) ^ ((r1 >> 2) & 3);
  const size_t gbase0 = (size_t)r0 * DIM + ((c0i ^ x0) << 3);
  const size_t gbase1 = (size_t)r1 * DIM + ((c1i ^ x1) << 3);
  unsigned short* ldst0 = As + i0 * 8;    // byte off i0*16
  unsigned short* ldst1 = As + i1 * 8;

#define STAGE(TI) { \
    const size_t toff = (size_t)((TI) >> 3) * (256*DIM) + ((TI) & 7) * 32; \
    gld16(cbb_l + gbase0 + toff, ldst0); \
    gld16(cbb_l + gbase1 + toff, ldst1); \
  }
#define gld16(g, l) __builtin_amdgcn_global_load_lds( \
      (const __attribute__((address_space(1))) unsigned int*)(g), \
      (__attribute__((address_space(3))) unsigned int*)(l), 16, 0, 0)

  // prologue: tile 0 in flight during B build
  STAGE(0)

  // ---- phase 0: residual rows -> LDS (exact fp32 chain -> bf16) --------
  {
    const int row = tid >> 3;
    const int d0 = (tid & 7) * 32;
    const int grow = rowbase + row;
    int hist[NLVL > 1 ? NLVL : 1];
#pragma unroll
    for (int j = 0; j < LVL; ++j) hist[j] = idxw[j * NROWS + grow];
#pragma unroll
    for (int c4 = 0; c4 < 4; ++c4){
      const int d = d0 + c4*8;
      const float* p = feat + (size_t)grow * DIM + d;
      float4 f0 = *reinterpret_cast<const float4*>(p);
      float4 f1 = *reinterpret_cast<const float4*>(p + 4);
#pragma unroll
      for (int j = 0; j < LVL; ++j){
        const float* cp = cb32 + ((size_t)j * KC + hist[j]) * DIM + d;
        const float4 c0 = *reinterpret_cast<const float4*>(cp);
        const float4 c1 = *reinterpret_cast<const float4*>(cp + 4);
        f0.x -= c0.x; f0.y -= c0.y; f0.z -= c0.z; f0.w -= c0.w;
        f1.x -= c1.x; f1.y -= c1.y; f1.z -= c1.z; f1.w -= c1.w;
      }
      bf16x8 b;
      b[0]=(short)f2b(f0.x); b[1]=(short)f2b(f0.y); b[2]=(short)f2b(f0.z); b[3]=(short)f2b(f0.w);
      b[4]=(short)f2b(f1.x); b[5]=(short)f2b(f1.y); b[6]=(short)f2b(f1.z); b[7]=(short)f2b(f1.w);
      *reinterpret_cast<bf16x8*>(&Bs[row*256 + (((d >> 3) ^ (row & 7)) << 3)]) = b;
    }
  }

  f32x4 acc[2][4];
#pragma unroll
  for (int mi = 0; mi < 2; ++mi)
#pragma unroll
    for (int ni = 0; ni < 4; ++ni) acc[mi][ni] = (f32x4){0.f,0.f,0.f,0.f};

  unsigned ks[2][4] = {{0xFFFFFFFFu,0xFFFFFFFFu,0xFFFFFFFFu,0xFFFFFFFFu},
                       {0xFFFFFFFFu,0xFFFFFFFFu,0xFFFFFFFFu,0xFFFFFFFFu}};

  // ---- per-lane LDS offsets, loop-invariant parts ----------------------
  int offA[4];
#pragma unroll
  for (int ni = 0; ni < 4; ++ni){
    const int arow = wc*64 + ni*16 + r16;
    const int xa = (arow & 3) ^ ((arow >> 2) & 3);
    offA[ni] = arow*32 + ((quad ^ xa) << 3);
  }
  // Bf offset decomposition: off(kt) = bB[mi] + ((kt ^ bx[mi]) << 5)
  int bB[2], bx[2];
#pragma unroll
  for (int mi = 0; mi < 2; ++mi){
    const int row = wr*32 + mi*16 + r16;
    const int rx = row & 7;
    bx[mi] = rx >> 2;
    bB[mi] = row*256 + ((quad ^ (rx & 3)) << 3);
  }

  __syncthreads();   // tile 0 drained; Bs complete

  for (int i = 0; i < 32; ++i){
    const int ct = i >> 3, kt = i & 7;

    // ---- read fragments of tile i (As holds tile i) --------------------
    bf16x8 Bf[2], Af[4];
#pragma unroll
    for (int mi = 0; mi < 2; ++mi)
      Bf[mi] = *reinterpret_cast<const bf16x8*>(
          &Bs[bB[mi] + ((kt ^ bx[mi]) << 5)]);
#pragma unroll
    for (int ni = 0; ni < 4; ++ni)
      Af[ni] = *reinterpret_cast<const bf16x8*>(&As[offA[ni]]);

    __syncthreads();                 // all reads done -> As overwrite safe
    if (i < 31) STAGE(i + 1)         // DMA in flight under MFMA below

#pragma unroll
    for (int ni = 0; ni < 4; ++ni){
      acc[0][ni] = __builtin_amdgcn_mfma_f32_16x16x32_bf16(Af[ni], Bf[0], acc[0][ni], 0, 0, 0);
      acc[1][ni] = __builtin_amdgcn_mfma_f32_16x16x32_bf16(Af[ni], Bf[1], acc[1][ni], 0, 0, 0);
    }

    if (kt == 7){
#pragma unroll
      for (int mi = 0; mi < 2; ++mi)
#pragma unroll
        for (int ni = 0; ni < 4; ++ni){
          const int c0 = ct*256 + wc*64 + ni*16 + quad*4;
          const float4 cn = *reinterpret_cast<const float4*>(cnx_l + c0);
          const f32x4 a = acc[mi][ni];
          ins4u(ks[mi], fkey(fmaf(-2.f, a[0], cn.x), c0+0));
          ins4u(ks[mi], fkey(fmaf(-2.f, a[1], cn.y), c0+1));
          ins4u(ks[mi], fkey(fmaf(-2.f, a[2], cn.z), c0+2));
          ins4u(ks[mi], fkey(fmaf(-2.f, a[3], cn.w), c0+3));
          acc[mi][ni] = (f32x4){0.f,0.f,0.f,0.f};
        }
    }
    __syncthreads();                 // DMA drained: As holds tile i+1
  }
#undef STAGE
#undef gld16

  // ---- rowmin publish + list init ---------------------------------------
#pragma unroll
  for (int mi = 0; mi < 2; ++mi){
    unsigned m = ks[mi][0];
    const unsigned o1 = (unsigned)__shfl_xor((int)m, 16);
    m = m < o1 ? m : o1;
    const unsigned o2 = (unsigned)__shfl_xor((int)m, 32);
    m = m < o2 ? m : o2;
    if (quad == 0) rowm[(wr*32 + mi*16 + r16)*4 + wc] = m;
  }
  if (tid < 64){ cnt_l[tid] = 0; ovf_l[tid] = 0; }
  __syncthreads();

  // ---- per-lane margin emission (lane-overflow -> hard) -----------------
#pragma unroll
  for (int mi = 0; mi < 2; ++mi){
    const int row = wr*32 + mi*16 + r16;
    unsigned m1 = rowm[row*4];
#pragma unroll
    for (int w = 1; w < 4; ++w){
      const unsigned o = rowm[row*4 + w];
      m1 = m1 < o ? m1 : o;
    }
    const unsigned thr = fkey(fdec(m1) + AMB, 1023);
#pragma unroll
    for (int e = 0; e < 4; ++e){
      if (ks[mi][e] <= thr){
        const int pos = atomicAdd(&cnt_l[row], 1);
        if (pos < 16) cand_l[row*16 + pos] = (int)(ks[mi][e] & 1023u);
      }
    }
    if (ks[mi][3] <= thr) ovf_l[row] = 1;   // lane may have dropped entries
  }
  __syncthreads();

  // ---- classify & emit --------------------------------------------------
  int apos = -1, hpos = -1, myc = 0;
  if (tid < 64){
    myc = cnt_l[tid];
    if (!ovf_l[tid] && myc == 1){
      idxw[LVL * NROWS + rowbase + tid] = cand_l[tid*16];
    } else if (!ovf_l[tid] && myc <= 16){
      apos = atomicAdd(&acnt_s, 1);
    } else {
      hpos = atomicAdd(&hcnt_s, 1);
    }
  }
  __syncthreads();
  if (tid == 0){
    abase_s = acnt_s ? atomicAdd(&cnt8[LVL], acnt_s) : 0;
    hbase_s = hcnt_s ? atomicAdd(&cnt8[4 + LVL], hcnt_s) : 0;
  }
  __syncthreads();
  if (apos >= 0){
    int* rp = arecs + (size_t)(abase_s + apos) * REC;
    rp[0] = rowbase + tid; rp[1] = myc;
    for (int e = 0; e < myc; ++e) rp[2+e] = cand_l[tid*16 + e];
  }
  if (hpos >= 0) hrows[hbase_s + hpos] = rowbase + tid;
}

// ---------------- K2a: amb rows (verbatim r12-r17, validated) -----------
template<int LVL>
__global__ __launch_bounds__(256)
void rvq_amb(const float* __restrict__ feat,
             const float* __restrict__ cb32,
             const float* __restrict__ cnx_l,
             int* __restrict__ idxw,
             const int* __restrict__ cnt8,
             const int* __restrict__ arecs)
{
  __shared__ float rres[16][260];
  const int tid = threadIdx.x;
  const int g = tid >> 4, q = tid & 15;
  const int cnt = cnt8[LVL];
  const float* cbl = cb32 + (size_t)LVL * KC * DIM;

  for (int rr = blockIdx.x * 16 + g; rr < cnt; rr += gridDim.x * 16){
    const int* rp = arecs + (size_t)rr * REC;
    const int grow = rp[0];
    const int c = rp[1];

    float4 rv[4];
#pragma unroll
    for (int i4 = 0; i4 < 4; ++i4){
      const int d = q*16 + i4*4;
      float4 w = *reinterpret_cast<const float4*>(feat + (size_t)grow * DIM + d);
#pragma unroll
      for (int j2 = 0; j2 < LVL; ++j2){
        const int kj = idxw[(size_t)j2 * NROWS + grow];
        const float4 cv = *reinterpret_cast<const float4*>(
            cb32 + ((size_t)j2 * KC + kj) * DIM + d);
        w.x -= cv.x; w.y -= cv.y; w.z -= cv.z; w.w -= cv.w;
      }
      rv[i4] = w;
      *reinterpret_cast<float4*>(&rres[g][d]) = w;
    }

    float m1 = FLT_MAX, m2 = FLT_MAX; int i1 = INT_MAX;
    for (int qq = 0; qq < c; ++qq){
      const int ci = rp[2+qq];
      const float* cp = cbl + (size_t)ci * DIM + q*16;
      float pa = 0.f;
#pragma unroll
      for (int j = 0; j < 4; ++j){
        const float4 cv = *reinterpret_cast<const float4*>(cp + j*4);
        pa = fmaf(rv[j].x, cv.x, pa); pa = fmaf(rv[j].y, cv.y, pa);
        pa = fmaf(rv[j].z, cv.z, pa); pa = fmaf(rv[j].w, cv.w, pa);
      }
#pragma unroll
      for (int m = 1; m < 16; m <<= 1) pa += __shfl_xor(pa, m);
      const float sc = cnx_l[ci] - 2.0f * pa;
      if (sless(sc, ci, m1, i1)){ m2 = m1; m1 = sc; i1 = ci; }
      else m2 = fminf(m2, sc);
    }

    int winner = i1;
    if (!(m2 - m1 > GUARD)){
      float bs = FLT_MAX; int bi = INT_MAX;
      for (int k = q; k < c; k += 16){
        const int ci = rp[2+k];
        float a = 0.f;
        for (int d4 = 0; d4 < 64; ++d4){
          const float4 cv = *reinterpret_cast<const float4*>(cbl + (size_t)ci * DIM + d4*4);
          const float4 rw = *reinterpret_cast<const float4*>(&rres[g][d4*4]);
          a = fmaf(rw.x, cv.x, a); a = fmaf(rw.y, cv.y, a);
          a = fmaf(rw.z, cv.z, a); a = fmaf(rw.w, cv.w, a);
        }
        const float sc = cnx_l[ci] - 2.0f * a;
        if (sless(sc, ci, bs, bi)){ bs = sc; bi = ci; }
      }
#pragma unroll
      for (int m = 1; m < 16; m <<= 1){
        const float ob = __shfl_xor(bs, m); const int oi = __shfl_xor(bi, m);
        if (sless(ob, oi, bs, bi)){ bs = ob; bi = oi; }
      }
      winner = bi;
    }
    if (q == 0) idxw[(size_t)LVL * NROWS + grow] = winner;
  }
}

// ---------------- K2b: hard rows (verbatim r11-r17, validated) ----------
template<int LVL>
__global__ __launch_bounds__(256)
void rvq_hard(const float* __restrict__ feat,
              const float* __restrict__ cb32,
              const float* __restrict__ cnx_l,
              int* __restrict__ idxw,
              const int* __restrict__ cnt8,
              const int* __restrict__ hrows)
{
  __shared__ float rres[260];
  __shared__ float scb[1024];
  __shared__ float wmn[4];
  __shared__ float wbs[4];
  __shared__ int   wbi[4];
  const int tid = threadIdx.x;
  const int g = tid >> 4, q = tid & 15;
  const int wv = tid >> 6, ln = tid & 63;
  const int cnt = cnt8[4 + LVL];
  const float* cbl = cb32 + (size_t)LVL * KC * DIM;

  for (int r = blockIdx.x; r < cnt; r += gridDim.x){
    const int grow = hrows[r];
    if (tid < 16){
#pragma unroll
      for (int i4 = 0; i4 < 4; ++i4){
        const int d = tid*16 + i4*4;
        float4 w = *reinterpret_cast<const float4*>(feat + (size_t)grow * DIM + d);
#pragma unroll
        for (int j2 = 0; j2 < LVL; ++j2){
          const int kj = idxw[(size_t)j2 * NROWS + grow];
          const float4 cv = *reinterpret_cast<const float4*>(
              cb32 + ((size_t)j2 * KC + kj) * DIM + d);
          w.x -= cv.x; w.y -= cv.y; w.z -= cv.z; w.w -= cv.w;
        }
        *reinterpret_cast<float4*>(&rres[d]) = w;
      }
    }
    __syncthreads();

    float4 rv[4];
#pragma unroll
    for (int j = 0; j < 4; ++j)
      rv[j] = *reinterpret_cast<const float4*>(&rres[q*16 + j*4]);

    for (int t = 0; t < 64; ++t){
      const int ci = g*64 + t;
      float pa = 0.f;
#pragma unroll
      for (int j = 0; j < 4; ++j){
        const float4 cv = *reinterpret_cast<const float4*>(
            cbl + (size_t)ci * DIM + q*16 + j*4);
        pa = fmaf(rv[j].x, cv.x, pa); pa = fmaf(rv[j].y, cv.y, pa);
        pa = fmaf(rv[j].z, cv.z, pa); pa = fmaf(rv[j].w, cv.w, pa);
      }
#pragma unroll
      for (int m = 1; m < 16; m <<= 1) pa += __shfl_xor(pa, m);
      if (q == 0) scb[ci] = cnx_l[ci] - 2.0f * pa;
    }
    __syncthreads();

    float mn = fminf(fminf(scb[tid], scb[tid+256]), fminf(scb[tid+512], scb[tid+768]));
#pragma unroll
    for (int m = 1; m < 64; m <<= 1) mn = fminf(mn, __shfl_xor(mn, m));
    if (ln == 0) wmn[wv] = mn;
    __syncthreads();
    const float m1p = fminf(fminf(wmn[0], wmn[1]), fminf(wmn[2], wmn[3]));
    const float thr = m1p + GUARD;

    float bs = FLT_MAX; int bi = INT_MAX;
#pragma unroll
    for (int k = 0; k < 4; ++k){
      const int ci = tid + k*256;
      if (scb[ci] <= thr){
        float a = 0.f;
        for (int d4 = 0; d4 < 64; ++d4){
          const float4 cv = *reinterpret_cast<const float4*>(cbl + (size_t)ci * DIM + d4*4);
          const float4 rw = *reinterpret_cast<const float4*>(&rres[d4*4]);
          a = fmaf(rw.x, cv.x, a); a = fmaf(rw.y, cv.y, a);
          a = fmaf(rw.z, cv.z, a); a = fmaf(rw.w, cv.w, a);
        }
        const float sc = cnx_l[ci] - 2.0f * a;
        if (sless(sc, ci, bs, bi)){ bs = sc; bi = ci; }
      }
    }
#pragma unroll
    for (int m = 1; m < 64; m <<= 1){
      const float ob = __shfl_xor(bs, m); const int oi = __shfl_xor(bi, m);
      if (sless(ob, oi, bs, bi)){ bs = ob; bi = oi; }
    }
    if (ln == 0){ wbs[wv] = bs; wbi[wv] = bi; }
    __syncthreads();
    if (tid == 0){
      float fb = wbs[0]; int fi = wbi[0];
#pragma unroll
      for (int w = 1; w < 4; ++w)
        if (sless(wbs[w], wbi[w], fb, fi)){ fb = wbs[w]; fi = wbi[w]; }
      idxw[(size_t)LVL * NROWS + grow] = fi;
    }
    __syncthreads();
  }
}

// ---------------- K3: final output = q0+q1+q2+q3 (validated r5-r17) -----
__global__ __launch_bounds__(256)
void rvq_out(const float* __restrict__ cb32,
             const int* __restrict__ idxw,
             float* __restrict__ out)
{
  const int tid = threadIdx.x;
  const int row = tid >> 4, sub = tid & 15;
  const size_t n = (size_t)blockIdx.x * 16 + row;
  int hist[NLVL];
#pragma unroll
  for (int j2 = 0; j2 < 4; ++j2) hist[j2] = idxw[(size_t)j2 * NROWS + n];
#pragma unroll
  for (int i = 0; i < 4; ++i){
    const int d = sub*4 + i*64;
    float4 a = *reinterpret_cast<const float4*>(
        cb32 + ((size_t)0 * KC + hist[0]) * DIM + d);
#pragma unroll
    for (int j2 = 1; j2 < 4; ++j2){
      const float4 qv = *reinterpret_cast<const float4*>(
          cb32 + ((size_t)j2 * KC + hist[j2]) * DIM + d);
      a.x += qv.x; a.y += qv.y; a.z += qv.z; a.w += qv.w;
    }
    *reinterpret_cast<float4*>(out + n*DIM + d) = a;
  }
}

extern "C" void kernel_launch(void* const* d_in, const int* in_sizes, int n_in,
                              void* d_out, int out_size, void* d_ws, size_t ws_size,
                              hipStream_t stream){
  const float* feat = (const float*)d_in[0];
  const float* cb32 = (const float*)d_in[1];
  float* out = (float*)d_out;

  char* ws = (char*)d_ws;
  float* cnx  = (float*)(ws);                              // 16 KB
  int*   cnt8 = (int*)(ws + 16384);                        // 8 counters
  unsigned short* cbb = (unsigned short*)(ws + 32768);     // 2 MB
  int*   idxw = (int*)(ws + 32768 + 2097152);              // 2 MB
  int*   arecs = (int*)(ws + 32768 + 2097152 + 2097152);   // 9.5 MB
  int*   hrows = (int*)(ws + 32768 + 2097152 + 2097152 + 9961472); // 512 KB

  zero8<<<1, 64, 0, stream>>>(cnt8);
  prep_cbb<<<1024, 256, 0, stream>>>(cb32, cbb);
  prep_cn<<<64, 64, 0, stream>>>(cb32, cnx);

#define LVL_STEP(L) \
  rvq_score<L><<<2048, 512, 0, stream>>>(feat, cb32, cbb + (size_t)L*KC*DIM, \
      cnx + L*KC, idxw, cnt8, arecs, hrows); \
  rvq_amb<L><<<2048, 256, 0, stream>>>(feat, cb32, cnx + L*KC, idxw, cnt8, arecs); \
  rvq_hard<L><<<512, 256, 0, stream>>>(feat, cb32, cnx + L*KC, idxw, cnt8, hrows);

  LVL_STEP(0)
  LVL_STEP(1)
  LVL_STEP(2)
  LVL_STEP(3)
#undef LVL_STEP

  rvq_out<<<8192, 256, 0, stream>>>(cb32, idxw, out);
}

// Round 19
// 1001.908 us; speedup vs baseline: 1.1497x; 1.0251x over previous
//
#include <hip/hip_runtime.h>
#include <hip/hip_bf16.h>
#include <float.h>
#include <limits.h>

#define NROWS 131072
#define DIM   256
#define NLVL  4
#define KC    1024
#define AMB   6.0f     // bf16-score ambiguity margin (validated r4-r18)
#define GUARD 0.25f    // parallel-vs-serial fp32 ordering guard (validated r10-r18)
#define REC   18       // amb record: row, cnt, cand[16]

typedef __attribute__((ext_vector_type(8))) short bf16x8;
typedef __attribute__((ext_vector_type(4))) float f32x4;
typedef __attribute__((ext_vector_type(4))) unsigned short us4;

__device__ __forceinline__ unsigned short f2b(float f){
  __hip_bfloat16 h = __float2bfloat16(f);
  return *reinterpret_cast<unsigned short*>(&h);
}

__device__ __forceinline__ float sqb(float x){
  float s = x * x;
  asm volatile("" : "+v"(s));
  return s;
}

__device__ __forceinline__ bool sless(float a, int ia, float b, int ib){
  return a < b || (a == b && ia < ib);
}

// monotone float->u32 key with 10-bit center index embedded in the low bits.
// (validated r18: truncation absorbed by AMB slack; exactness via K2.)
__device__ __forceinline__ unsigned fkey(float s, int ci){
  unsigned u = __builtin_bit_cast(unsigned, s);
  u ^= (unsigned)((int)u >> 31) | 0x80000000u;
  return (u & 0xFFFFFC00u) | (unsigned)ci;
}
__device__ __forceinline__ float fdec(unsigned k){
  const unsigned u = (k & 0x80000000u) ? (k ^ 0x80000000u) : ~k;
  return __builtin_bit_cast(float, u);
}

// branch-free keep-4-smallest insert (7 min/max ops on u32 keys)
__device__ __forceinline__ void ins4u(unsigned (&s)[4], unsigned k){
  s[3] = s[3] < k ? s[3] : k;
#pragma unroll
  for (int j = 3; j >= 1; --j){
    const unsigned lo = s[j-1] < s[j] ? s[j-1] : s[j];
    const unsigned hi = s[j-1] < s[j] ? s[j] : s[j-1];
    s[j-1] = lo; s[j] = hi;
  }
}

// ---------------- prep kernels (validated r4-r18) -----------------------
__global__ void zero8(int* __restrict__ p){
  if (threadIdx.x < 8) p[threadIdx.x] = 0;
}

__global__ void prep_cbb(const float* __restrict__ cb, unsigned short* __restrict__ cbb){
  const int wave = threadIdx.x >> 6, lane = threadIdx.x & 63;
  const int c = blockIdx.x * 4 + wave;
  const size_t off = (size_t)c * DIM + lane * 4;
  const float4 v = *reinterpret_cast<const float4*>(cb + off);
  us4 u = { f2b(v.x), f2b(v.y), f2b(v.z), f2b(v.w) };
  *reinterpret_cast<us4*>(cbb + off) = u;
}

__global__ void prep_cn(const float* __restrict__ cb, float* __restrict__ cnx){
  const int c = blockIdx.x * 64 + threadIdx.x;
  const float* p = cb + (size_t)c * DIM;
  float blk[2];
  for (int b = 0; b < 2; ++b){
    float r[8];
#pragma unroll
    for (int j = 0; j < 8; ++j) r[j] = sqb(p[b*128 + j]);
    for (int i = 8; i < 128; i += 8)
#pragma unroll
      for (int j = 0; j < 8; ++j) r[j] += sqb(p[b*128 + i + j]);
    blk[b] = ((r[0]+r[1]) + (r[2]+r[3])) + ((r[4]+r[5]) + (r[6]+r[7]));
  }
  cnx[c] = blk[0] + blk[1];
}

// ---------------- K1: LDS-tiled GEMM + u32-key lane-top4 classify -------
// r18 semantics verbatim; As double-buffered -> ONE barrier per K-step
// (barrier proves DMA-drain into buf^1 AND reads-done on buf).
template<int LVL>
__global__ __launch_bounds__(512, 4)
void rvq_score(const float* __restrict__ feat,
               const float* __restrict__ cb32,
               const unsigned short* __restrict__ cbb_l,
               const float* __restrict__ cnx_l,
               int* __restrict__ idxw,
               int* __restrict__ cnt8,      // [0..3] amb, [4..7] hard
               int* __restrict__ arecs,     // [*][REC]
               int* __restrict__ hrows)
{
  __shared__ __align__(16) char smem[65536];
  unsigned short* Bs = (unsigned short*)smem;            // 32 KB
  unsigned short* As = (unsigned short*)(smem + 32768);  // 2 x 16 KB (linear)
  // aliases into As region (dead after main loop):
  unsigned* rowm = (unsigned*)(smem + 32768);            // [64*4]
  int*   cnt_l = (int*)(smem + 32768 + 1024);            // [64]
  int*   ovf_l = (int*)(smem + 32768 + 1280);            // [64]
  int*   cand_l= (int*)(smem + 32768 + 1536);            // [64*16]
  __shared__ int acnt_s, hcnt_s, abase_s, hbase_s;

  const int tid  = threadIdx.x;
  const int lane = tid & 63;
  const int wave = tid >> 6;
  const int r16  = lane & 15, quad = lane >> 4;
  const int wr   = wave >> 2, wc = wave & 3;
  const int rowbase = (int)blockIdx.x * 64;

  if (tid == 0){ acnt_s = 0; hcnt_s = 0; }

  // ---- per-thread staging constants (slot i -> (r,c); src chunk = c^x(r))
  const int i0 = tid,        r0 = i0 >> 2, c0i = i0 & 3;
  const int i1 = 512 + tid,  r1 = i1 >> 2, c1i = i1 & 3;
  const int x0 = (r0 & 3) ^ ((r0 >> 2) & 3);
  const int x1 = (r1 & 3) ^ ((r1 >> 2) & 3);
  const size_t gbase0 = (size_t)r0 * DIM + ((c0i ^ x0) << 3);
  const size_t gbase1 = (size_t)r1 * DIM + ((c1i ^ x1) << 3);
  unsigned short* ldst0 = As + i0 * 8;    // byte off i0*16
  unsigned short* ldst1 = As + i1 * 8;

#define gld16(g, l) __builtin_amdgcn_global_load_lds( \
      (const __attribute__((address_space(1))) unsigned int*)(g), \
      (__attribute__((address_space(3))) unsigned int*)(l), 16, 0, 0)
#define STAGE(TI, B) { \
    const size_t toff = (size_t)((TI) >> 3) * (256*DIM) + ((TI) & 7) * 32; \
    gld16(cbb_l + gbase0 + toff, ldst0 + (B)*8192); \
    gld16(cbb_l + gbase1 + toff, ldst1 + (B)*8192); \
  }

  // prologue: tile 0 in flight during B build
  STAGE(0, 0)

  // ---- phase 0: residual rows -> LDS (exact fp32 chain -> bf16) --------
  {
    const int row = tid >> 3;
    const int d0 = (tid & 7) * 32;
    const int grow = rowbase + row;
    int hist[NLVL > 1 ? NLVL : 1];
#pragma unroll
    for (int j = 0; j < LVL; ++j) hist[j] = idxw[j * NROWS + grow];
#pragma unroll
    for (int c4 = 0; c4 < 4; ++c4){
      const int d = d0 + c4*8;
      const float* p = feat + (size_t)grow * DIM + d;
      float4 f0 = *reinterpret_cast<const float4*>(p);
      float4 f1 = *reinterpret_cast<const float4*>(p + 4);
#pragma unroll
      for (int j = 0; j < LVL; ++j){
        const float* cp = cb32 + ((size_t)j * KC + hist[j]) * DIM + d;
        const float4 c0 = *reinterpret_cast<const float4*>(cp);
        const float4 c1 = *reinterpret_cast<const float4*>(cp + 4);
        f0.x -= c0.x; f0.y -= c0.y; f0.z -= c0.z; f0.w -= c0.w;
        f1.x -= c1.x; f1.y -= c1.y; f1.z -= c1.z; f1.w -= c1.w;
      }
      bf16x8 b;
      b[0]=(short)f2b(f0.x); b[1]=(short)f2b(f0.y); b[2]=(short)f2b(f0.z); b[3]=(short)f2b(f0.w);
      b[4]=(short)f2b(f1.x); b[5]=(short)f2b(f1.y); b[6]=(short)f2b(f1.z); b[7]=(short)f2b(f1.w);
      *reinterpret_cast<bf16x8*>(&Bs[row*256 + (((d >> 3) ^ (row & 7)) << 3)]) = b;
    }
  }

  f32x4 acc[2][4];
#pragma unroll
  for (int mi = 0; mi < 2; ++mi)
#pragma unroll
    for (int ni = 0; ni < 4; ++ni) acc[mi][ni] = (f32x4){0.f,0.f,0.f,0.f};

  unsigned ks[2][4] = {{0xFFFFFFFFu,0xFFFFFFFFu,0xFFFFFFFFu,0xFFFFFFFFu},
                       {0xFFFFFFFFu,0xFFFFFFFFu,0xFFFFFFFFu,0xFFFFFFFFu}};

  // ---- per-lane LDS offsets, loop-invariant parts ----------------------
  int offA[4];
#pragma unroll
  for (int ni = 0; ni < 4; ++ni){
    const int arow = wc*64 + ni*16 + r16;
    const int xa = (arow & 3) ^ ((arow >> 2) & 3);
    offA[ni] = arow*32 + ((quad ^ xa) << 3);
  }
  // Bf offset decomposition: off(kt) = bB[mi] + ((kt ^ bx[mi]) << 5)
  int bB[2], bx[2];
#pragma unroll
  for (int mi = 0; mi < 2; ++mi){
    const int row = wr*32 + mi*16 + r16;
    const int rx = row & 7;
    bx[mi] = rx >> 2;
    bB[mi] = row*256 + ((quad ^ (rx & 3)) << 3);
  }

  __syncthreads();   // tile 0 drained into As[0]; Bs complete

  int buf = 0;
  for (int i = 0; i < 32; ++i){
    const int ct = i >> 3, kt = i & 7;

    // ---- read fragments of tile i from As[buf] -------------------------
    bf16x8 Bf[2], Af[4];
#pragma unroll
    for (int mi = 0; mi < 2; ++mi)
      Bf[mi] = *reinterpret_cast<const bf16x8*>(
          &Bs[bB[mi] + ((kt ^ bx[mi]) << 5)]);
#pragma unroll
    for (int ni = 0; ni < 4; ++ni)
      Af[ni] = *reinterpret_cast<const bf16x8*>(&As[buf*8192 + offA[ni]]);

    // ---- issue next tile's DMA into the other buffer (no barrier) ------
    if (i < 31) STAGE(i + 1, buf ^ 1)

#pragma unroll
    for (int ni = 0; ni < 4; ++ni){
      acc[0][ni] = __builtin_amdgcn_mfma_f32_16x16x32_bf16(Af[ni], Bf[0], acc[0][ni], 0, 0, 0);
      acc[1][ni] = __builtin_amdgcn_mfma_f32_16x16x32_bf16(Af[ni], Bf[1], acc[1][ni], 0, 0, 0);
    }

    if (kt == 7){
#pragma unroll
      for (int mi = 0; mi < 2; ++mi)
#pragma unroll
        for (int ni = 0; ni < 4; ++ni){
          const int c0 = ct*256 + wc*64 + ni*16 + quad*4;
          const float4 cn = *reinterpret_cast<const float4*>(cnx_l + c0);
          const f32x4 a = acc[mi][ni];
          ins4u(ks[mi], fkey(fmaf(-2.f, a[0], cn.x), c0+0));
          ins4u(ks[mi], fkey(fmaf(-2.f, a[1], cn.y), c0+1));
          ins4u(ks[mi], fkey(fmaf(-2.f, a[2], cn.z), c0+2));
          ins4u(ks[mi], fkey(fmaf(-2.f, a[3], cn.w), c0+3));
          acc[mi][ni] = (f32x4){0.f,0.f,0.f,0.f};
        }
    }
    // single barrier: drains DMA into As[buf^1] (vmcnt 0 before s_barrier)
    // AND proves all waves finished reading As[buf] before it's re-staged.
    __syncthreads();
    buf ^= 1;
  }
#undef STAGE
#undef gld16

  // ---- rowmin publish + list init (validated r18) ----------------------
#pragma unroll
  for (int mi = 0; mi < 2; ++mi){
    unsigned m = ks[mi][0];
    const unsigned o1 = (unsigned)__shfl_xor((int)m, 16);
    m = m < o1 ? m : o1;
    const unsigned o2 = (unsigned)__shfl_xor((int)m, 32);
    m = m < o2 ? m : o2;
    if (quad == 0) rowm[(wr*32 + mi*16 + r16)*4 + wc] = m;
  }
  if (tid < 64){ cnt_l[tid] = 0; ovf_l[tid] = 0; }
  __syncthreads();

  // ---- per-lane margin emission (lane-overflow -> hard) -----------------
#pragma unroll
  for (int mi = 0; mi < 2; ++mi){
    const int row = wr*32 + mi*16 + r16;
    unsigned m1 = rowm[row*4];
#pragma unroll
    for (int w = 1; w < 4; ++w){
      const unsigned o = rowm[row*4 + w];
      m1 = m1 < o ? m1 : o;
    }
    const unsigned thr = fkey(fdec(m1) + AMB, 1023);
#pragma unroll
    for (int e = 0; e < 4; ++e){
      if (ks[mi][e] <= thr){
        const int pos = atomicAdd(&cnt_l[row], 1);
        if (pos < 16) cand_l[row*16 + pos] = (int)(ks[mi][e] & 1023u);
      }
    }
    if (ks[mi][3] <= thr) ovf_l[row] = 1;   // lane may have dropped entries
  }
  __syncthreads();

  // ---- classify & emit --------------------------------------------------
  int apos = -1, hpos = -1, myc = 0;
  if (tid < 64){
    myc = cnt_l[tid];
    if (!ovf_l[tid] && myc == 1){
      idxw[LVL * NROWS + rowbase + tid] = cand_l[tid*16];
    } else if (!ovf_l[tid] && myc <= 16){
      apos = atomicAdd(&acnt_s, 1);
    } else {
      hpos = atomicAdd(&hcnt_s, 1);
    }
  }
  __syncthreads();
  if (tid == 0){
    abase_s = acnt_s ? atomicAdd(&cnt8[LVL], acnt_s) : 0;
    hbase_s = hcnt_s ? atomicAdd(&cnt8[4 + LVL], hcnt_s) : 0;
  }
  __syncthreads();
  if (apos >= 0){
    int* rp = arecs + (size_t)(abase_s + apos) * REC;
    rp[0] = rowbase + tid; rp[1] = myc;
    for (int e = 0; e < myc; ++e) rp[2+e] = cand_l[tid*16 + e];
  }
  if (hpos >= 0) hrows[hbase_s + hpos] = rowbase + tid;
}

// ---------------- K2a: amb rows (verbatim r12-r18, validated) -----------
template<int LVL>
__global__ __launch_bounds__(256)
void rvq_amb(const float* __restrict__ feat,
             const float* __restrict__ cb32,
             const float* __restrict__ cnx_l,
             int* __restrict__ idxw,
             const int* __restrict__ cnt8,
             const int* __restrict__ arecs)
{
  __shared__ float rres[16][260];
  const int tid = threadIdx.x;
  const int g = tid >> 4, q = tid & 15;
  const int cnt = cnt8[LVL];
  const float* cbl = cb32 + (size_t)LVL * KC * DIM;

  for (int rr = blockIdx.x * 16 + g; rr < cnt; rr += gridDim.x * 16){
    const int* rp = arecs + (size_t)rr * REC;
    const int grow = rp[0];
    const int c = rp[1];

    float4 rv[4];
#pragma unroll
    for (int i4 = 0; i4 < 4; ++i4){
      const int d = q*16 + i4*4;
      float4 w = *reinterpret_cast<const float4*>(feat + (size_t)grow * DIM + d);
#pragma unroll
      for (int j2 = 0; j2 < LVL; ++j2){
        const int kj = idxw[(size_t)j2 * NROWS + grow];
        const float4 cv = *reinterpret_cast<const float4*>(
            cb32 + ((size_t)j2 * KC + kj) * DIM + d);
        w.x -= cv.x; w.y -= cv.y; w.z -= cv.z; w.w -= cv.w;
      }
      rv[i4] = w;
      *reinterpret_cast<float4*>(&rres[g][d]) = w;
    }

    float m1 = FLT_MAX, m2 = FLT_MAX; int i1 = INT_MAX;
    for (int qq = 0; qq < c; ++qq){
      const int ci = rp[2+qq];
      const float* cp = cbl + (size_t)ci * DIM + q*16;
      float pa = 0.f;
#pragma unroll
      for (int j = 0; j < 4; ++j){
        const float4 cv = *reinterpret_cast<const float4*>(cp + j*4);
        pa = fmaf(rv[j].x, cv.x, pa); pa = fmaf(rv[j].y, cv.y, pa);
        pa = fmaf(rv[j].z, cv.z, pa); pa = fmaf(rv[j].w, cv.w, pa);
      }
#pragma unroll
      for (int m = 1; m < 16; m <<= 1) pa += __shfl_xor(pa, m);
      const float sc = cnx_l[ci] - 2.0f * pa;
      if (sless(sc, ci, m1, i1)){ m2 = m1; m1 = sc; i1 = ci; }
      else m2 = fminf(m2, sc);
    }

    int winner = i1;
    if (!(m2 - m1 > GUARD)){
      float bs = FLT_MAX; int bi = INT_MAX;
      for (int k = q; k < c; k += 16){
        const int ci = rp[2+k];
        float a = 0.f;
        for (int d4 = 0; d4 < 64; ++d4){
          const float4 cv = *reinterpret_cast<const float4*>(cbl + (size_t)ci * DIM + d4*4);
          const float4 rw = *reinterpret_cast<const float4*>(&rres[g][d4*4]);
          a = fmaf(rw.x, cv.x, a); a = fmaf(rw.y, cv.y, a);
          a = fmaf(rw.z, cv.z, a); a = fmaf(rw.w, cv.w, a);
        }
        const float sc = cnx_l[ci] - 2.0f * a;
        if (sless(sc, ci, bs, bi)){ bs = sc; bi = ci; }
      }
#pragma unroll
      for (int m = 1; m < 16; m <<= 1){
        const float ob = __shfl_xor(bs, m); const int oi = __shfl_xor(bi, m);
        if (sless(ob, oi, bs, bi)){ bs = ob; bi = oi; }
      }
      winner = bi;
    }
    if (q == 0) idxw[(size_t)LVL * NROWS + grow] = winner;
  }
}

// ---------------- K2b: hard rows (verbatim r11-r18, validated) ----------
template<int LVL>
__global__ __launch_bounds__(256)
void rvq_hard(const float* __restrict__ feat,
              const float* __restrict__ cb32,
              const float* __restrict__ cnx_l,
              int* __restrict__ idxw,
              const int* __restrict__ cnt8,
              const int* __restrict__ hrows)
{
  __shared__ float rres[260];
  __shared__ float scb[1024];
  __shared__ float wmn[4];
  __shared__ float wbs[4];
  __shared__ int   wbi[4];
  const int tid = threadIdx.x;
  const int g = tid >> 4, q = tid & 15;
  const int wv = tid >> 6, ln = tid & 63;
  const int cnt = cnt8[4 + LVL];
  const float* cbl = cb32 + (size_t)LVL * KC * DIM;

  for (int r = blockIdx.x; r < cnt; r += gridDim.x){
    const int grow = hrows[r];
    if (tid < 16){
#pragma unroll
      for (int i4 = 0; i4 < 4; ++i4){
        const int d = tid*16 + i4*4;
        float4 w = *reinterpret_cast<const float4*>(feat + (size_t)grow * DIM + d);
#pragma unroll
        for (int j2 = 0; j2 < LVL; ++j2){
          const int kj = idxw[(size_t)j2 * NROWS + grow];
          const float4 cv = *reinterpret_cast<const float4*>(
              cb32 + ((size_t)j2 * KC + kj) * DIM + d);
          w.x -= cv.x; w.y -= cv.y; w.z -= cv.z; w.w -= cv.w;
        }
        *reinterpret_cast<float4*>(&rres[d]) = w;
      }
    }
    __syncthreads();

    float4 rv[4];
#pragma unroll
    for (int j = 0; j < 4; ++j)
      rv[j] = *reinterpret_cast<const float4*>(&rres[q*16 + j*4]);

    for (int t = 0; t < 64; ++t){
      const int ci = g*64 + t;
      float pa = 0.f;
#pragma unroll
      for (int j = 0; j < 4; ++j){
        const float4 cv = *reinterpret_cast<const float4*>(
            cbl + (size_t)ci * DIM + q*16 + j*4);
        pa = fmaf(rv[j].x, cv.x, pa); pa = fmaf(rv[j].y, cv.y, pa);
        pa = fmaf(rv[j].z, cv.z, pa); pa = fmaf(rv[j].w, cv.w, pa);
      }
#pragma unroll
      for (int m = 1; m < 16; m <<= 1) pa += __shfl_xor(pa, m);
      if (q == 0) scb[ci] = cnx_l[ci] - 2.0f * pa;
    }
    __syncthreads();

    float mn = fminf(fminf(scb[tid], scb[tid+256]), fminf(scb[tid+512], scb[tid+768]));
#pragma unroll
    for (int m = 1; m < 64; m <<= 1) mn = fminf(mn, __shfl_xor(mn, m));
    if (ln == 0) wmn[wv] = mn;
    __syncthreads();
    const float m1p = fminf(fminf(wmn[0], wmn[1]), fminf(wmn[2], wmn[3]));
    const float thr = m1p + GUARD;

    float bs = FLT_MAX; int bi = INT_MAX;
#pragma unroll
    for (int k = 0; k < 4; ++k){
      const int ci = tid + k*256;
      if (scb[ci] <= thr){
        float a = 0.f;
        for (int d4 = 0; d4 < 64; ++d4){
          const float4 cv = *reinterpret_cast<const float4*>(cbl + (size_t)ci * DIM + d4*4);
          const float4 rw = *reinterpret_cast<const float4*>(&rres[d4*4]);
          a = fmaf(rw.x, cv.x, a); a = fmaf(rw.y, cv.y, a);
          a = fmaf(rw.z, cv.z, a); a = fmaf(rw.w, cv.w, a);
        }
        const float sc = cnx_l[ci] - 2.0f * a;
        if (sless(sc, ci, bs, bi)){ bs = sc; bi = ci; }
      }
    }
#pragma unroll
    for (int m = 1; m < 64; m <<= 1){
      const float ob = __shfl_xor(bs, m); const int oi = __shfl_xor(bi, m);
      if (sless(ob, oi, bs, bi)){ bs = ob; bi = oi; }
    }
    if (ln == 0){ wbs[wv] = bs; wbi[wv] = bi; }
    __syncthreads();
    if (tid == 0){
      float fb = wbs[0]; int fi = wbi[0];
#pragma unroll
      for (int w = 1; w < 4; ++w)
        if (sless(wbs[w], wbi[w], fb, fi)){ fb = wbs[w]; fi = wbi[w]; }
      idxw[(size_t)LVL * NROWS + grow] = fi;
    }
    __syncthreads();
  }
}

// ---------------- K3: final output = q0+q1+q2+q3 (validated r5-r18) -----
__global__ __launch_bounds__(256)
void rvq_out(const float* __restrict__ cb32,
             const int* __restrict__ idxw,
             float* __restrict__ out)
{
  const int tid = threadIdx.x;
  const int row = tid >> 4, sub = tid & 15;
  const size_t n = (size_t)blockIdx.x * 16 + row;
  int hist[NLVL];
#pragma unroll
  for (int j2 = 0; j2 < 4; ++j2) hist[j2] = idxw[(size_t)j2 * NROWS + n];
#pragma unroll
  for (int i = 0; i < 4; ++i){
    const int d = sub*4 + i*64;
    float4 a = *reinterpret_cast<const float4*>(
        cb32 + ((size_t)0 * KC + hist[0]) * DIM + d);
#pragma unroll
    for (int j2 = 1; j2 < 4; ++j2){
      const float4 qv = *reinterpret_cast<const float4*>(
          cb32 + ((size_t)j2 * KC + hist[j2]) * DIM + d);
      a.x += qv.x; a.y += qv.y; a.z += qv.z; a.w += qv.w;
    }
    *reinterpret_cast<float4*>(out + n*DIM + d) = a;
  }
}

extern "C" void kernel_launch(void* const* d_in, const int* in_sizes, int n_in,
                              void* d_out, int out_size, void* d_ws, size_t ws_size,
                              hipStream_t stream){
  const float* feat = (const float*)d_in[0];
  const float* cb32 = (const float*)d_in[1];
  float* out = (float*)d_out;

  char* ws = (char*)d_ws;
  float* cnx  = (float*)(ws);                              // 16 KB
  int*   cnt8 = (int*)(ws + 16384);                        // 8 counters
  unsigned short* cbb = (unsigned short*)(ws + 32768);     // 2 MB
  int*   idxw = (int*)(ws + 32768 + 2097152);              // 2 MB
  int*   arecs = (int*)(ws + 32768 + 2097152 + 2097152);   // 9.5 MB
  int*   hrows = (int*)(ws + 32768 + 2097152 + 2097152 + 9961472); // 512 KB

  zero8<<<1, 64, 0, stream>>>(cnt8);
  prep_cbb<<<1024, 256, 0, stream>>>(cb32, cbb);
  prep_cn<<<64, 64, 0, stream>>>(cb32, cnx);

#define LVL_STEP(L) \
  rvq_score<L><<<2048, 512, 0, stream>>>(feat, cb32, cbb + (size_t)L*KC*DIM, \
      cnx + L*KC, idxw, cnt8, arecs, hrows); \
  rvq_amb<L><<<2048, 256, 0, stream>>>(feat, cb32, cnx + L*KC, idxw, cnt8, arecs); \
  rvq_hard<L><<<512, 256, 0, stream>>>(feat, cb32, cnx + L*KC, idxw, cnt8, hrows);

  LVL_STEP(0)
  LVL_STEP(1)
  LVL_STEP(2)
  LVL_STEP(3)
#undef LVL_STEP

  rvq_out<<<8192, 256, 0, stream>>>(cb32, idxw, out);
}